// Round 13
// baseline (791.373 us; speedup 1.0000x reference)
//
#include <hip/hip_runtime.h>

typedef unsigned short us;
typedef us us4 __attribute__((ext_vector_type(4)));
typedef us us8 __attribute__((ext_vector_type(8)));
typedef short bf16x8 __attribute__((ext_vector_type(8)));
typedef float f32x4 __attribute__((ext_vector_type(4)));

#define DEVI static __device__ __forceinline__

// constants for this problem instance
#define BB 16
#define NN 4096
#define PP 256
#define CC 8
#define MM (BB * NN)   // 65536

DEVI float bf2f(us u) { unsigned x = ((unsigned)u) << 16; return __builtin_bit_cast(float, x); }
DEVI us f2bf(float f) {
  unsigned x = __builtin_bit_cast(unsigned, f);
  x += 0x7fffu + ((x >> 16) & 1u);   // round to nearest even
  return (us)(x >> 16);
}

DEVI void gload_lds16(const void* g, void* l) {
  __builtin_amdgcn_global_load_lds(
      (const __attribute__((address_space(1))) void*)g,
      (__attribute__((address_space(3))) void*)l, 16, 0, 0);
}

DEVI float sigf(float x) { return 1.f / (1.f + __expf(-x)); }
DEVI float tanhfast(float a) {
  float aa = fabsf(a);
  float t = 1.f - 2.f / (1.f + __expf(2.f * aa));
  return copysignf(t, a);
}

DEVI void raw_barrier() {
  __builtin_amdgcn_sched_barrier(0);
  __builtin_amdgcn_s_barrier();      // RAW barrier: no implicit vmcnt(0) drain
  __builtin_amdgcn_sched_barrier(0);
}

// ---------------- weight prep: fp32 -> bf16, concatenated / gate-interleaved ----
// Wg layout (shuffle-free): row R -> J16 = R>>6, gate g = (R>>4)&3, c = R&15,
// output col j = J16*16 + c. Over K=512 ([h | s]):
//   g=0 (r):  [W_ih_r | W_hh_r]   g=1 (z): [W_ih_z | W_hh_z]
//   g=2 (xn): [W_ih_n | 0]        g=3 (hn): [0 | W_hh_n]
__global__ void k_prep(const float* __restrict__ Wres,
                       const float* __restrict__ Wpar, const float* __restrict__ bpar,
                       const float* __restrict__ Wnbr, const float* __restrict__ bnbr,
                       const float* __restrict__ Wih, const float* __restrict__ Whh,
                       const float* __restrict__ bih, const float* __restrict__ bhh,
                       us* __restrict__ Wr, us* __restrict__ Wcat, float* __restrict__ bcat,
                       us* __restrict__ Wg, float* __restrict__ bg) {
  int tid = blockIdx.x * blockDim.x + threadIdx.x;
  int nth = gridDim.x * blockDim.x;
  for (int i = tid; i < 256 * 256; i += nth) Wr[i] = f2bf(Wres[i]);
  for (int i = tid; i < 256 * 512; i += nth) {
    int o = i >> 9, k = i & 511;
    float v = (k < 256) ? Wpar[o * 256 + k] : Wnbr[o * 256 + (k - 256)];
    Wcat[i] = f2bf(v);
  }
  for (int i = tid; i < 256; i += nth) bcat[i] = bpar[i] + bnbr[i];
  for (int i = tid; i < 1024 * 512; i += nth) {
    int R = i >> 9, k = i & 511;
    int g = (R >> 4) & 3, j = ((R >> 6) << 4) + (R & 15);
    float v = 0.f;
    if (g == 0)      v = (k < 256) ? Wih[j * 256 + k]         : Whh[j * 256 + (k - 256)];
    else if (g == 1) v = (k < 256) ? Wih[(256 + j) * 256 + k] : Whh[(256 + j) * 256 + (k - 256)];
    else if (g == 2) v = (k < 256) ? Wih[(512 + j) * 256 + k] : 0.f;
    else             v = (k < 256) ? 0.f                      : Whh[(512 + j) * 256 + (k - 256)];
    Wg[i] = f2bf(v);
  }
  for (int i = tid; i < 1024; i += nth) {
    int g = (i >> 4) & 3, j = ((i >> 6) << 4) + (i & 15);
    float v;
    if (g == 0)      v = bih[j] + bhh[j];
    else if (g == 1) v = bih[256 + j] + bhh[256 + j];
    else if (g == 2) v = bih[512 + j];
    else             v = bhh[512 + j];
    bg[i] = v;
  }
}

// ---------------- x fp32 -> bf16 (vectorized) ----------------
__global__ __launch_bounds__(256) void k_f2bf(const float* __restrict__ x,
                                              us* __restrict__ o, int n8) {
  int i = blockIdx.x * blockDim.x + threadIdx.x;
  if (i >= n8) return;
  const float4* p = (const float4*)x + (size_t)i * 2;
  float4 a = p[0], b = p[1];
  us8 r;
  r[0] = f2bf(a.x); r[1] = f2bf(a.y); r[2] = f2bf(a.z); r[3] = f2bf(a.w);
  r[4] = f2bf(b.x); r[5] = f2bf(b.y); r[6] = f2bf(b.z); r[7] = f2bf(b.w);
  *(us8*)(o + (size_t)i * 8) = r;
}

// ---------------- children-avg: nbr[m] = avg(h[children(m)]) (bf16) ------------
__global__ __launch_bounds__(256)
void k_child(const us* __restrict__ h, const int* __restrict__ chd,
             const int* __restrict__ cnt, us* __restrict__ nbr) {
  int wid = (blockIdx.x * blockDim.x + threadIdx.x) >> 6;  // one wave per node
  int l = threadIdx.x & 63;
  int m = wid;                       // 0..MM-1
  int b = m >> 12;                   // N = 4096
  int c = cnt[m];
  float inv = 1.f / (float)c;
  const int* ch = chd + (size_t)m * CC;
  us4 cv[CC];
#pragma unroll
  for (int i = 0; i < CC; ++i) {
    int rowC = (b << 12) + ch[i];
    cv[i] = *((const us4*)(h + ((size_t)rowC << 8)) + l);
  }
  float a0 = 0.f, a1 = 0.f, a2 = 0.f, a3 = 0.f;
#pragma unroll
  for (int i = 0; i < CC; ++i) {
    float wgt = (i < c) ? 1.f : 0.f;
    a0 += wgt * bf2f(cv[i][0]); a1 += wgt * bf2f(cv[i][1]);
    a2 += wgt * bf2f(cv[i][2]); a3 += wgt * bf2f(cv[i][3]);
  }
  us4 nb;
  nb[0] = f2bf(a0 * inv); nb[1] = f2bf(a1 * inv);
  nb[2] = f2bf(a2 * inv); nb[3] = f2bf(a3 * inv);
  *((us4*)(nbr + ((size_t)m << 8)) + l) = nb;
}

// ---------------- B fragments: global(L2-hot) -> VGPR, MFMA layout -------------
template <int M4>
DEVI void loadBr(const us* __restrict__ Bw, int rowBase, int l, int kt, int KT,
                 bf16x8 (&b)[2][4]) {
#pragma unroll
  for (int ks = 0; ks < 2; ++ks)
#pragma unroll
    for (int j = 0; j < 4; ++j)
      if (M4 & (1 << j)) {
        int row = rowBase + j * 16 + (l & 15);
        b[ks][j] = *(const bf16x8*)(Bw + (size_t)row * KT + kt + ks * 32 + ((l >> 4) * 8));
      }
}

// ---------------- MFMA K-tile: A (256 rows) from LDS (swizzled), B from regs ---
template <int M4>
DEVI void mma8r(const us* As, int wr, int l, const bf16x8 (&b)[2][4],
                f32x4 (&acc)[8][4]) {
#pragma unroll
  for (int ks = 0; ks < 2; ++ks) {
    bf16x8 af[8];
#pragma unroll
    for (int i = 0; i < 8; ++i) {
      int row = wr * 128 + i * 16 + (l & 15);
      int kb = ((ks * 32 + (l >> 4) * 8) * 2) ^ ((row & 7) << 4);  // swizzled read
      af[i] = *(const bf16x8*)((const char*)As + row * 128 + kb);
    }
#pragma unroll
    for (int i = 0; i < 8; ++i)
#pragma unroll
      for (int j = 0; j < 4; ++j)
        if (M4 & (1 << j))
          acc[i][j] = __builtin_amdgcn_mfma_f32_16x16x32_bf16(af[i], b[ks][j], acc[i][j], 0, 0, 0);
  }
}

// ---------------- MFMA K-tile: A direct global->VGPR (L2/L3-hot), B from regs --
// Per-lane 16B loads (16 rows x 64B per wave-instr) — uncoalesced but L2-served;
// trades 4x L2 requests for ZERO staging barriers. Bit-identical A values.
template <int M4>
DEVI void mma_hdir(const us* __restrict__ h, int rowBase, int l, int kt,
                   const bf16x8 (&b)[2][4], f32x4 (&acc)[8][4]) {
#pragma unroll
  for (int ks = 0; ks < 2; ++ks) {
    bf16x8 af[8];
#pragma unroll
    for (int i = 0; i < 8; ++i) {
      int row = rowBase + i * 16 + (l & 15);
      af[i] = *(const bf16x8*)(h + (size_t)row * 256 + kt + ks * 32 + ((l >> 4) * 8));
    }
#pragma unroll
    for (int i = 0; i < 8; ++i)
#pragma unroll
      for (int j = 0; j < 4; ++j)
        if (M4 & (1 << j))
          acc[i][j] = __builtin_amdgcn_mfma_f32_16x16x32_bf16(af[i], b[ks][j], acc[i][j], 0, 0, 0);
  }
}

// ---------------- FUSED per-iteration kernel: s-GEMM + GRU-gates GEMM ----------
// R13 (fusion v3). R12 failed from (a) 256-reg spill (WRITE 180 MB) and
// (b) phase-2 vmcnt(0) drains + hbuf serialization + agent-scope sF loads.
// v3 phase 2 is BARRIER-FREE: s resident in LDS (written by epilogue-1, read
// all nt with no further sync); h direct global->VGPR (no hbuf at all); Wg via
// regs; sF via plain loads (same block wrote it -> same-CU L1/L2 hot). bs/bh
// live in disjoint scopes (<=24 VGPR each) to stay under the 256-reg cap.
// LDS: s_lds 4x32 KB = 128 KB ([0],[1] double as phase-1 staging dbuf).
// NOTE: never >2 waves/SIMD — acc is 128 regs (R2: spill, 3x slow).
template <int FINAL>
__global__ __launch_bounds__(512, 2)
void k_fused(const us* __restrict__ h, const us* __restrict__ nbr,
             const int* __restrict__ par,
             const us* __restrict__ Wcat, const float* __restrict__ bcat,
             const us* __restrict__ Wg, const float* __restrict__ bg,
             us* __restrict__ outBf, float* __restrict__ outF,
             float* __restrict__ sF) {
  __shared__ __align__(16) us s_lds[4][256 * 64];  // 128 KB
  int tid = threadIdx.x;
  int w = tid >> 6, l = tid & 63;
  int wr = w >> 2, wc = w & 3;
  int bid = blockIdx.x;
  int per = gridDim.x >> 3;
  int mi = (bid & 7) * per + (bid >> 3);           // XCD-chunked
  int mBase = mi * 256;
  f32x4 acc[8][4] = {};

  // ---- phase 1: s = [h[par] | nbr] @ Wcat^T ----
  {
    int prow[4];
    int bb = (mBase >> 12) << 12;
#pragma unroll
    for (int c = 0; c < 4; ++c)
      prow[c] = bb + par[mBase + c * 64 + (tid >> 3)];

    auto stage1 = [&](int t) {        // A=[h[par] | nbr], k-tile t -> s_lds[t&1]
      int kt = t * 64, buf = t & 1;
#pragma unroll
      for (int c = 0; c < 4; ++c) {
        int row = c * 64 + (tid >> 3);
        int kb = ((tid & 7) * 16) ^ ((row & 7) << 4);
        const char* ga;
        if (kt < 256) ga = (const char*)(h + (size_t)prow[c] * 256 + kt) + kb;
        else          ga = (const char*)(nbr + (size_t)(mBase + row) * 256 + (kt - 256)) + kb;
        gload_lds16(ga, (char*)s_lds[buf] + row * 128 + (tid & 7) * 16);
      }
    };

    bf16x8 bfr[2][4];
    stage1(0);
#pragma unroll
    for (int t = 0; t < 8; ++t) {
      loadBr<0b1111>(Wcat, wc * 64, l, t * 64, 512, bfr);
      if (t < 7) {
        stage1(t + 1);
        asm volatile("s_waitcnt vmcnt(4)" ::: "memory");  // A(t)+B(t) done; A(t+1) in flight
      } else {
        asm volatile("s_waitcnt vmcnt(0)" ::: "memory");
      }
      raw_barrier();
      mma8r<0b1111>(s_lds[t & 1], wr, l, bfr, acc);
      raw_barrier();
    }
  }

  // ---- epilogue 1: sF (f32 global) + s (bf16 -> LDS, staged layout, buf wc) ---
#pragma unroll
  for (int i = 0; i < 8; ++i)
#pragma unroll
    for (int j = 0; j < 4; ++j) {
      int col = wc * 64 + j * 16 + (l & 15);
      int row0 = wr * 128 + i * 16 + ((l >> 4) << 2);
      float bb2 = bcat[col];
#pragma unroll
      for (int e = 0; e < 4; ++e) {
        float v = acc[i][j][e] + bb2;
        int row = row0 + e;
        sF[(size_t)(mBase + row) * 256 + col] = v;
        int byte = ((j * 16 + (l & 15)) * 2) ^ ((row & 7) << 4);
        *(us*)((char*)s_lds[wc] + row * 128 + byte) = f2bf(v);
      }
    }
  // boundary: all waves' s ds_writes + sF stores complete before phase 2
  asm volatile("s_waitcnt vmcnt(0) lgkmcnt(0)" ::: "memory");
  raw_barrier();

  // ---- phase 2: gates = [h|s] @ Wg^T, 4 n-subtiles, ZERO barriers ----
  int rowA = mBase + wr * 128;
#pragma unroll
  for (int nt = 0; nt < 4; ++nt) {
#pragma unroll
    for (int i = 0; i < 8; ++i)
#pragma unroll
      for (int j = 0; j < 4; ++j) acc[i][j] = f32x4{0.f, 0.f, 0.f, 0.f};
    int rowB = (nt * 4 + wc) * 64;   // this wave's Wg gate-row block
#pragma unroll
    for (int q = 0; q < 4; ++q) {
      {  // s-part: A from resident LDS (j-mask 0b1011: r, z, hn gates)
        bf16x8 bs[2][4];
        loadBr<0b1011>(Wg, rowB, l, 256 + q * 64, 512, bs);
        mma8r<0b1011>(s_lds[q], wr, l, bs, acc);
      }
      {  // h-part: A direct from global (j-mask 0b0111: r, z, xn gates)
        bf16x8 bh[2][4];
        loadBr<0b0111>(Wg, rowB, l, q * 64, 512, bh);
        mma_hdir<0b0111>(h, rowA, l, q * 64, bh, acc);
      }
    }
    // ---- epilogue 2 (subtile nt): GRU gates + blend with sv (f32, L1-hot) ----
    int outCol = (nt * 4 + wc) * 16 + (l & 15);
    float b0 = bg[rowB + 0  + (l & 15)];
    float b1 = bg[rowB + 16 + (l & 15)];
    float b2 = bg[rowB + 32 + (l & 15)];
    float b3 = bg[rowB + 48 + (l & 15)];
#pragma unroll
    for (int i = 0; i < 8; ++i) {
      int row0 = rowA + i * 16 + ((l >> 4) << 2);
#pragma unroll
      for (int e = 0; e < 4; ++e) {
        float r = sigf(acc[i][0][e] + b0);
        float z = sigf(acc[i][1][e] + b1);
        float n = tanhfast(acc[i][2][e] + b2 + r * (acc[i][3][e] + b3));
        size_t off = (size_t)(row0 + e) * 256 + outCol;
        float sv = sF[off];
        float o = (1.f - z) * n + z * sv;
        if (FINAL) outF[off] = o;
        else       outBf[off] = f2bf(o);
      }
    }
  }
}

// ---------------- standalone GEMM (resize only), R6/R10 core -------------------
__global__ __launch_bounds__(512, 2)
void k_gemm0(const us* __restrict__ A0, const us* __restrict__ Bw,
             const float* __restrict__ bias, us* __restrict__ outBf) {
  __shared__ __align__(16) us As[2][256 * 64];
  __shared__ __align__(16) us Bs[2][256 * 64];
  int tid = threadIdx.x;
  int w = tid >> 6, l = tid & 63;
  int wr = w >> 2, wc = w & 3;
  int bid = blockIdx.x;
  int per = gridDim.x >> 3;
  int mi = (bid & 7) * per + (bid >> 3);
  int mBase = mi * 256;
  f32x4 acc[8][4] = {};

  auto stage = [&](int t) {
    int kt = t * 64, buf = t & 1;
#pragma unroll
    for (int c = 0; c < 4; ++c) {
      int row = c * 64 + (tid >> 3);
      int kb = ((tid & 7) * 16) ^ ((row & 7) << 4);
      const char* ga = (const char*)(A0 + (size_t)(mBase + row) * 256 + kt) + kb;
      gload_lds16(ga, (char*)As[buf] + row * 128 + (tid & 7) * 16);
      const char* gb = (const char*)(Bw + (size_t)row * 256 + kt) + kb;
      gload_lds16(gb, (char*)Bs[buf] + row * 128 + (tid & 7) * 16);
    }
  };

  stage(0);
#pragma unroll
  for (int t = 0; t < 4; ++t) {
    if (t + 1 < 4) {
      stage(t + 1);
      asm volatile("s_waitcnt vmcnt(8)" ::: "memory");
    } else {
      asm volatile("s_waitcnt vmcnt(0)" ::: "memory");
    }
    raw_barrier();
    int buf = t & 1;
    {
      bf16x8 af[8], bfr2[4];
#pragma unroll
      for (int ks = 0; ks < 2; ++ks) {
#pragma unroll
        for (int i = 0; i < 8; ++i) {
          int row = wr * 128 + i * 16 + (l & 15);
          int kb = ((ks * 32 + (l >> 4) * 8) * 2) ^ ((row & 7) << 4);
          af[i] = *(const bf16x8*)((const char*)As[buf] + row * 128 + kb);
        }
#pragma unroll
        for (int j = 0; j < 4; ++j) {
          int row = wc * 64 + j * 16 + (l & 15);
          int kb = ((ks * 32 + (l >> 4) * 8) * 2) ^ ((row & 7) << 4);
          bfr2[j] = *(const bf16x8*)((const char*)Bs[buf] + row * 128 + kb);
        }
#pragma unroll
        for (int i = 0; i < 8; ++i)
#pragma unroll
          for (int j = 0; j < 4; ++j)
            acc[i][j] = __builtin_amdgcn_mfma_f32_16x16x32_bf16(af[i], bfr2[j], acc[i][j], 0, 0, 0);
      }
    }
    raw_barrier();
  }

  int rBase0 = mBase + wr * 128;
  int cBase0 = wc * 64;
#pragma unroll
  for (int i = 0; i < 8; ++i)
#pragma unroll
    for (int j = 0; j < 4; ++j) {
      int col = cBase0 + j * 16 + (l & 15);
      int row0 = rBase0 + i * 16 + ((l >> 4) << 2);
      float bb = bias[col];
#pragma unroll
      for (int e = 0; e < 4; ++e)
        outBf[(size_t)(row0 + e) * 256 + col] = f2bf(acc[i][j][e] + bb);
    }
}

extern "C" void kernel_launch(void* const* d_in, const int* in_sizes, int n_in,
                              void* d_out, int out_size, void* d_ws, size_t ws_size,
                              hipStream_t stream) {
  const float* x    = (const float*)d_in[0];
  const int*   par  = (const int*)d_in[1];
  const int*   chd  = (const int*)d_in[2];
  const int*   cnt  = (const int*)d_in[3];
  const float* Wres = (const float*)d_in[4];
  const float* bres = (const float*)d_in[5];
  const float* Wpar = (const float*)d_in[6];
  const float* bpar = (const float*)d_in[7];
  const float* Wnbr = (const float*)d_in[8];
  const float* bnbr = (const float*)d_in[9];
  const float* Wih  = (const float*)d_in[10];
  const float* Whh  = (const float*)d_in[11];
  const float* bih  = (const float*)d_in[12];
  const float* bhh  = (const float*)d_in[13];

  char* ws = (char*)d_ws;
  size_t off = 0;
  auto alloc = [&](size_t sz) { char* p = ws + off; off += (sz + 255) & ~(size_t)255; return p; };
  us*    Wg   = (us*)alloc((size_t)1024 * 512 * 2);
  us*    Wcat = (us*)alloc((size_t)256 * 512 * 2);
  us*    Wr   = (us*)alloc((size_t)256 * 256 * 2);
  float* bcat = (float*)alloc(256 * 4);
  float* bg   = (float*)alloc(1024 * 4);
  us*    xbf  = (us*)alloc((size_t)MM * 256 * 2);
  us*    h0   = (us*)alloc((size_t)MM * 256 * 2);
  us*    h1   = (us*)alloc((size_t)MM * 256 * 2);
  us*    nbr  = (us*)alloc((size_t)MM * 256 * 2);
  float* sF   = (float*)d_out;  // f32 s scratch lives in d_out (final iter
                                // overwrites each slot after its own sv read)

  k_prep<<<256, 256, 0, stream>>>(Wres, Wpar, bpar, Wnbr, bnbr, Wih, Whh, bih, bhh,
                                  Wr, Wcat, bcat, Wg, bg);
  k_f2bf<<<(MM * 256 / 8) / 256, 256, 0, stream>>>(x, xbf, MM * 256 / 8);

  // h0 = x @ W_resize^T + b_resize
  k_gemm0<<<256, 512, 0, stream>>>(xbf, Wr, bres, h0);

  us* hc = h0;
  for (int it = 0; it < 3; ++it) {
    us* hn = (hc == h0) ? h1 : h0;
    k_child<<<MM / 4, 256, 0, stream>>>(hc, chd, cnt, nbr);
    if (it < 2)
      k_fused<0><<<256, 512, 0, stream>>>(hc, nbr, par, Wcat, bcat, Wg, bg,
                                          hn, nullptr, sF);
    else
      k_fused<1><<<256, 512, 0, stream>>>(hc, nbr, par, Wcat, bcat, Wg, bg,
                                          nullptr, (float*)d_out, sF);
    hc = hn;
  }
}

// Round 14
// 720.719 us; speedup vs baseline: 1.0980x; 1.0980x over previous
//
#include <hip/hip_runtime.h>

typedef unsigned short us;
typedef us us4 __attribute__((ext_vector_type(4)));
typedef us us8 __attribute__((ext_vector_type(8)));
typedef short bf16x8 __attribute__((ext_vector_type(8)));
typedef float f32x4 __attribute__((ext_vector_type(4)));

#define DEVI static __device__ __forceinline__

// constants for this problem instance
#define BB 16
#define NN 4096
#define PP 256
#define CC 8
#define MM (BB * NN)   // 65536

DEVI float bf2f(us u) { unsigned x = ((unsigned)u) << 16; return __builtin_bit_cast(float, x); }
DEVI us f2bf(float f) {
  unsigned x = __builtin_bit_cast(unsigned, f);
  x += 0x7fffu + ((x >> 16) & 1u);   // round to nearest even
  return (us)(x >> 16);
}

DEVI void gload_lds16(const void* g, void* l) {
  __builtin_amdgcn_global_load_lds(
      (const __attribute__((address_space(1))) void*)g,
      (__attribute__((address_space(3))) void*)l, 16, 0, 0);
}

DEVI float sigf(float x) { return 1.f / (1.f + __expf(-x)); }
DEVI float tanhfast(float a) {
  float aa = fabsf(a);
  float t = 1.f - 2.f / (1.f + __expf(2.f * aa));
  return copysignf(t, a);
}

// ---------------- weight prep: fp32 -> bf16, concatenated / gate-interleaved ----
// Wg layout (shuffle-free): row R -> J16 = R>>6, gate g = (R>>4)&3, c = R&15,
// output col j = J16*16 + c. Over K=512 ([h | s]):
//   g=0 (r):  [W_ih_r | W_hh_r]   g=1 (z): [W_ih_z | W_hh_z]
//   g=2 (xn): [W_ih_n | 0]        g=3 (hn): [0 | W_hh_n]
__global__ void k_prep(const float* __restrict__ Wres,
                       const float* __restrict__ Wpar, const float* __restrict__ bpar,
                       const float* __restrict__ Wnbr, const float* __restrict__ bnbr,
                       const float* __restrict__ Wih, const float* __restrict__ Whh,
                       const float* __restrict__ bih, const float* __restrict__ bhh,
                       us* __restrict__ Wr, us* __restrict__ Wcat, float* __restrict__ bcat,
                       us* __restrict__ Wg, float* __restrict__ bg) {
  int tid = blockIdx.x * blockDim.x + threadIdx.x;
  int nth = gridDim.x * blockDim.x;
  for (int i = tid; i < 256 * 256; i += nth) Wr[i] = f2bf(Wres[i]);
  for (int i = tid; i < 256 * 512; i += nth) {
    int o = i >> 9, k = i & 511;
    float v = (k < 256) ? Wpar[o * 256 + k] : Wnbr[o * 256 + (k - 256)];
    Wcat[i] = f2bf(v);
  }
  for (int i = tid; i < 256; i += nth) bcat[i] = bpar[i] + bnbr[i];
  for (int i = tid; i < 1024 * 512; i += nth) {
    int R = i >> 9, k = i & 511;
    int g = (R >> 4) & 3, j = ((R >> 6) << 4) + (R & 15);
    float v = 0.f;
    if (g == 0)      v = (k < 256) ? Wih[j * 256 + k]         : Whh[j * 256 + (k - 256)];
    else if (g == 1) v = (k < 256) ? Wih[(256 + j) * 256 + k] : Whh[(256 + j) * 256 + (k - 256)];
    else if (g == 2) v = (k < 256) ? Wih[(512 + j) * 256 + k] : 0.f;
    else             v = (k < 256) ? 0.f                      : Whh[(512 + j) * 256 + (k - 256)];
    Wg[i] = f2bf(v);
  }
  for (int i = tid; i < 1024; i += nth) {
    int g = (i >> 4) & 3, j = ((i >> 6) << 4) + (i & 15);
    float v;
    if (g == 0)      v = bih[j] + bhh[j];
    else if (g == 1) v = bih[256 + j] + bhh[256 + j];
    else if (g == 2) v = bih[512 + j];
    else             v = bhh[512 + j];
    bg[i] = v;
  }
}

// ---------------- x fp32 -> bf16 (vectorized) ----------------
__global__ __launch_bounds__(256) void k_f2bf(const float* __restrict__ x,
                                              us* __restrict__ o, int n8) {
  int i = blockIdx.x * blockDim.x + threadIdx.x;
  if (i >= n8) return;
  const float4* p = (const float4*)x + (size_t)i * 2;
  float4 a = p[0], b = p[1];
  us8 r;
  r[0] = f2bf(a.x); r[1] = f2bf(a.y); r[2] = f2bf(a.z); r[3] = f2bf(a.w);
  r[4] = f2bf(b.x); r[5] = f2bf(b.y); r[6] = f2bf(b.z); r[7] = f2bf(b.w);
  *(us8*)(o + (size_t)i * 8) = r;
}

// ---------------- children-avg: nbr[m] = avg(h[children(m)]) (bf16) ------------
__global__ __launch_bounds__(256)
void k_child(const us* __restrict__ h, const int* __restrict__ chd,
             const int* __restrict__ cnt, us* __restrict__ nbr) {
  int wid = (blockIdx.x * blockDim.x + threadIdx.x) >> 6;  // one wave per node
  int l = threadIdx.x & 63;
  int m = wid;                       // 0..MM-1
  int b = m >> 12;                   // N = 4096
  int c = cnt[m];
  float inv = 1.f / (float)c;
  const int* ch = chd + (size_t)m * CC;
  us4 cv[CC];
#pragma unroll
  for (int i = 0; i < CC; ++i) {
    int rowC = (b << 12) + ch[i];
    cv[i] = *((const us4*)(h + ((size_t)rowC << 8)) + l);
  }
  float a0 = 0.f, a1 = 0.f, a2 = 0.f, a3 = 0.f;
#pragma unroll
  for (int i = 0; i < CC; ++i) {
    float wgt = (i < c) ? 1.f : 0.f;
    a0 += wgt * bf2f(cv[i][0]); a1 += wgt * bf2f(cv[i][1]);
    a2 += wgt * bf2f(cv[i][2]); a3 += wgt * bf2f(cv[i][3]);
  }
  us4 nb;
  nb[0] = f2bf(a0 * inv); nb[1] = f2bf(a1 * inv);
  nb[2] = f2bf(a2 * inv); nb[3] = f2bf(a3 * inv);
  *((us4*)(nbr + ((size_t)m << 8)) + l) = nb;
}

// ---------------- B fragments: global(L2-hot) -> VGPR, MFMA layout -------------
template <int M4>
DEVI void loadBr(const us* __restrict__ Bw, int rowBase, int l, int kt, int KT,
                 bf16x8 (&b)[2][4]) {
#pragma unroll
  for (int ks = 0; ks < 2; ++ks)
#pragma unroll
    for (int j = 0; j < 4; ++j)
      if (M4 & (1 << j)) {
        int row = rowBase + j * 16 + (l & 15);
        b[ks][j] = *(const bf16x8*)(Bw + (size_t)row * KT + kt + ks * 32 + ((l >> 4) * 8));
      }
}

// ---------------- MFMA k-tile: A (64 rows of 128-row tile) from LDS ------------
template <int M4>
DEVI void mma4r(const us* As, int wr, int l, const bf16x8 (&b)[2][4],
                f32x4 (&acc)[4][4]) {
#pragma unroll
  for (int ks = 0; ks < 2; ++ks) {
    bf16x8 af[4];
#pragma unroll
    for (int i = 0; i < 4; ++i) {
      int row = wr * 64 + i * 16 + (l & 15);
      int kb = ((ks * 32 + (l >> 4) * 8) * 2) ^ ((row & 7) << 4);  // swizzled read
      af[i] = *(const bf16x8*)((const char*)As + row * 128 + kb);
    }
#pragma unroll
    for (int i = 0; i < 4; ++i)
#pragma unroll
      for (int j = 0; j < 4; ++j)
        if (M4 & (1 << j))
          acc[i][j] = __builtin_amdgcn_mfma_f32_16x16x32_bf16(af[i], b[ks][j], acc[i][j], 0, 0, 0);
  }
}

// ---------------- A-RESIDENT single-barrier GEMM (R14) -------------------------
// 128-row m-tile; ALL of A ([128][KTOT] bf16, <=128 KB) staged to LDS once:
// 16 gload_lds/thread -> vmcnt(0) -> ONE barrier -> entire compute barrier-free
// (waves free-run; full ILP; no lockstep). A read from global EXACTLY once
// (R10's k-tile-paced core staged each A panel 4x and crossed 16 barriers).
// B (weights, L2-hot) global->VGPR fragments. 8 waves = 2(M)x4(N); per-wave
// acc[4][4] (64 regs) per n-subtile. EPI2 loops 4 n-subtiles (gate groups).
// masks: EPI2 skips hn (j=3) on h-half k-tiles, xn (j=2) on s-half.
// NOTE: never >2 waves/SIMD requested; reg estimate ~150 incl. 64 AGPR.
template <int EPI, int KTOT, int KSPLIT, bool GA>
__global__ __launch_bounds__(512, 2)
void k_half(const us* __restrict__ A0, const us* __restrict__ A1,
            const us* __restrict__ Bw, const float* __restrict__ bias,
            us* __restrict__ outBf, float* __restrict__ outF,
            const float* __restrict__ sF, int writeF32,
            const int* __restrict__ par) {
  constexpr int NQ = KTOT / 64, KS64 = KSPLIT / 64;
  constexpr int NT = (EPI == 2) ? 4 : 1;
  constexpr int MASKA = (EPI == 2) ? 0b0111 : 0b1111;
  constexpr int MASKB = (EPI == 2) ? 0b1011 : 0b1111;
  __shared__ __align__(16) us sA[NQ][128 * 64];   // 16 KB per k-tile
  int tid = threadIdx.x;
  int w = tid >> 6, l = tid & 63;
  int wr = w >> 2, wc = w & 3;
  int bid = blockIdx.x;
  int per = gridDim.x >> 3;
  int mi = (bid & 7) * per + (bid >> 3);           // XCD-chunked
  int mBase = mi * 128;

  // parent-gathered row per staging row (GA: h-half of EPI1's A)
  int prow[2];
  if (GA) {
    int bb = (mBase >> 12) << 12;
#pragma unroll
    for (int c = 0; c < 2; ++c)
      prow[c] = bb + par[mBase + c * 64 + (tid >> 3)];
  }

  // ---- stage ALL of A (once) ----
#pragma unroll
  for (int q = 0; q < NQ; ++q) {
    const us* src; int kOff;
    if (q < KS64) { src = A0; kOff = q * 64; }
    else          { src = A1; kOff = (q - KS64) * 64; }
#pragma unroll
    for (int c = 0; c < 2; ++c) {
      int row = c * 64 + (tid >> 3);
      int kb = ((tid & 7) * 16) ^ ((row & 7) << 4);   // pre-swizzled global source
      const char* ga;
      if (GA && q < KS64)
        ga = (const char*)(src + (size_t)prow[c] * 256 + kOff) + kb;
      else
        ga = (const char*)(src + (size_t)(mBase + row) * 256 + kOff) + kb;
      gload_lds16(ga, (char*)sA[q] + row * 128 + (tid & 7) * 16);
    }
  }
  asm volatile("s_waitcnt vmcnt(0)" ::: "memory");
  __syncthreads();                    // the ONLY barrier in this kernel

  // ---- compute: NT n-subtiles x NQ k-tiles, barrier-free ----
#pragma unroll
  for (int nt = 0; nt < NT; ++nt) {
    f32x4 acc[4][4] = {};
    int rowB = (EPI == 2) ? (nt * 4 + wc) * 64 : wc * 64;
#pragma unroll
    for (int q = 0; q < KS64; ++q) {
      bf16x8 bfr[2][4];
      loadBr<MASKA>(Bw, rowB, l, q * 64, KTOT, bfr);
      mma4r<MASKA>(sA[q], wr, l, bfr, acc);
    }
#pragma unroll
    for (int q = KS64; q < NQ; ++q) {
      bf16x8 bfr[2][4];
      loadBr<MASKB>(Bw, rowB, l, q * 64, KTOT, bfr);
      mma4r<MASKB>(sA[q], wr, l, bfr, acc);
    }
    if (EPI == 0 || EPI == 1) {
#pragma unroll
      for (int i = 0; i < 4; ++i)
#pragma unroll
        for (int j = 0; j < 4; ++j) {
          int col = wc * 64 + j * 16 + (l & 15);
          int row0 = mBase + wr * 64 + i * 16 + ((l >> 4) << 2);
          float bb = bias[col];
#pragma unroll
          for (int e = 0; e < 4; ++e) {
            float v = acc[i][j][e] + bb;
            size_t off = (size_t)(row0 + e) * 256 + col;
            outBf[off] = f2bf(v);
            if (EPI == 1) outF[off] = v;
          }
        }
    } else {
      // shuffle-free GRU epilogue: j-fragment == gate
      int outCol = (nt * 4 + wc) * 16 + (l & 15);
      float b0 = bias[rowB + 0  + (l & 15)];
      float b1 = bias[rowB + 16 + (l & 15)];
      float b2 = bias[rowB + 32 + (l & 15)];
      float b3 = bias[rowB + 48 + (l & 15)];
#pragma unroll
      for (int i = 0; i < 4; ++i) {
        int row0 = mBase + wr * 64 + i * 16 + ((l >> 4) << 2);
#pragma unroll
        for (int e = 0; e < 4; ++e) {
          float r = sigf(acc[i][0][e] + b0);
          float z = sigf(acc[i][1][e] + b1);
          float n = tanhfast(acc[i][2][e] + b2 + r * (acc[i][3][e] + b3));
          size_t off = (size_t)(row0 + e) * 256 + outCol;
          float sv = sF[off];
          float o = (1.f - z) * n + z * sv;
          if (writeF32) outF[off] = o;
          else          outBf[off] = f2bf(o);
        }
      }
    }
  }
}

extern "C" void kernel_launch(void* const* d_in, const int* in_sizes, int n_in,
                              void* d_out, int out_size, void* d_ws, size_t ws_size,
                              hipStream_t stream) {
  const float* x    = (const float*)d_in[0];
  const int*   par  = (const int*)d_in[1];
  const int*   chd  = (const int*)d_in[2];
  const int*   cnt  = (const int*)d_in[3];
  const float* Wres = (const float*)d_in[4];
  const float* bres = (const float*)d_in[5];
  const float* Wpar = (const float*)d_in[6];
  const float* bpar = (const float*)d_in[7];
  const float* Wnbr = (const float*)d_in[8];
  const float* bnbr = (const float*)d_in[9];
  const float* Wih  = (const float*)d_in[10];
  const float* Whh  = (const float*)d_in[11];
  const float* bih  = (const float*)d_in[12];
  const float* bhh  = (const float*)d_in[13];

  char* ws = (char*)d_ws;
  size_t off = 0;
  auto alloc = [&](size_t sz) { char* p = ws + off; off += (sz + 255) & ~(size_t)255; return p; };
  us*    Wg   = (us*)alloc((size_t)1024 * 512 * 2);
  us*    Wcat = (us*)alloc((size_t)256 * 512 * 2);
  us*    Wr   = (us*)alloc((size_t)256 * 256 * 2);
  float* bcat = (float*)alloc(256 * 4);
  float* bg   = (float*)alloc(1024 * 4);
  us*    xbf  = (us*)alloc((size_t)MM * 256 * 2);  // reused as s_bf after resize
  us*    h0   = (us*)alloc((size_t)MM * 256 * 2);
  us*    h1   = (us*)alloc((size_t)MM * 256 * 2);
  us*    nbr  = (us*)alloc((size_t)MM * 256 * 2);
  us*    sbf  = xbf;
  float* sF   = (float*)d_out;  // f32 s scratch lives in d_out (final iter
                                // overwrites each slot after its own sv read)

  k_prep<<<256, 256, 0, stream>>>(Wres, Wpar, bpar, Wnbr, bnbr, Wih, Whh, bih, bhh,
                                  Wr, Wcat, bcat, Wg, bg);
  k_f2bf<<<(MM * 256 / 8) / 256, 256, 0, stream>>>(x, xbf, MM * 256 / 8);

  // h0 = x @ W_resize^T + b_resize   (64 KB A-resident, 2 blocks/CU)
  k_half<0, 256, 256, false><<<MM / 128, 512, 0, stream>>>(
      xbf, xbf, Wr, bres, h0, nullptr, nullptr, 0, nullptr);

  us* hc = h0;
  for (int it = 0; it < 3; ++it) {
    us* hn = (hc == h0) ? h1 : h0;
    k_child<<<MM / 4, 256, 0, stream>>>(hc, chd, cnt, nbr);
    // s = [h[par] | nbr] @ Wcat^T + bcat  (parent gather fused into staging)
    k_half<1, 512, 256, true><<<MM / 128, 512, 0, stream>>>(
        hc, nbr, Wcat, bcat, sbf, sF, nullptr, 0, par);
    // fused GRU: [h|s] @ Wg^T, gate epilogue -> h_next (bf16) or d_out (f32)
    k_half<2, 512, 256, false><<<MM / 128, 512, 0, stream>>>(
        hc, sbf, Wg, bg, hn, (float*)d_out, sF, (it == 2) ? 1 : 0, nullptr);
    hc = hn;
  }
}

// Round 15
// 508.409 us; speedup vs baseline: 1.5566x; 1.4176x over previous
//
#include <hip/hip_runtime.h>

typedef unsigned short us;
typedef us us4 __attribute__((ext_vector_type(4)));
typedef us us8 __attribute__((ext_vector_type(8)));
typedef short bf16x8 __attribute__((ext_vector_type(8)));
typedef float f32x4 __attribute__((ext_vector_type(4)));

#define DEVI static __device__ __forceinline__

// constants for this problem instance
#define BB 16
#define NN 4096
#define PP 256
#define CC 8
#define MM (BB * NN)   // 65536

DEVI float bf2f(us u) { unsigned x = ((unsigned)u) << 16; return __builtin_bit_cast(float, x); }
DEVI us f2bf(float f) {
  unsigned x = __builtin_bit_cast(unsigned, f);
  x += 0x7fffu + ((x >> 16) & 1u);   // round to nearest even
  return (us)(x >> 16);
}

DEVI void gload_lds16(const void* g, void* l) {
  __builtin_amdgcn_global_load_lds(
      (const __attribute__((address_space(1))) void*)g,
      (__attribute__((address_space(3))) void*)l, 16, 0, 0);
}

DEVI float sigf(float x) { return 1.f / (1.f + __expf(-x)); }
DEVI float tanhfast(float a) {
  float aa = fabsf(a);
  float t = 1.f - 2.f / (1.f + __expf(2.f * aa));
  return copysignf(t, a);
}

// ---------------- weight prep: fp32 -> bf16, concatenated / gate-interleaved ----
// Wg layout (shuffle-free): row R -> J16 = R>>6, gate g = (R>>4)&3, c = R&15,
// output col j = J16*16 + c. Over K=512 ([h | s]):
//   g=0 (r):  [W_ih_r | W_hh_r]   g=1 (z): [W_ih_z | W_hh_z]
//   g=2 (xn): [W_ih_n | 0]        g=3 (hn): [0 | W_hh_n]
__global__ void k_prep(const float* __restrict__ Wres,
                       const float* __restrict__ Wpar, const float* __restrict__ bpar,
                       const float* __restrict__ Wnbr, const float* __restrict__ bnbr,
                       const float* __restrict__ Wih, const float* __restrict__ Whh,
                       const float* __restrict__ bih, const float* __restrict__ bhh,
                       us* __restrict__ Wr, us* __restrict__ Wcat, float* __restrict__ bcat,
                       us* __restrict__ Wg, float* __restrict__ bg) {
  int tid = blockIdx.x * blockDim.x + threadIdx.x;
  int nth = gridDim.x * blockDim.x;
  for (int i = tid; i < 256 * 256; i += nth) Wr[i] = f2bf(Wres[i]);
  for (int i = tid; i < 256 * 512; i += nth) {
    int o = i >> 9, k = i & 511;
    float v = (k < 256) ? Wpar[o * 256 + k] : Wnbr[o * 256 + (k - 256)];
    Wcat[i] = f2bf(v);
  }
  for (int i = tid; i < 256; i += nth) bcat[i] = bpar[i] + bnbr[i];
  for (int i = tid; i < 1024 * 512; i += nth) {
    int R = i >> 9, k = i & 511;
    int g = (R >> 4) & 3, j = ((R >> 6) << 4) + (R & 15);
    float v = 0.f;
    if (g == 0)      v = (k < 256) ? Wih[j * 256 + k]         : Whh[j * 256 + (k - 256)];
    else if (g == 1) v = (k < 256) ? Wih[(256 + j) * 256 + k] : Whh[(256 + j) * 256 + (k - 256)];
    else if (g == 2) v = (k < 256) ? Wih[(512 + j) * 256 + k] : 0.f;
    else             v = (k < 256) ? 0.f                      : Whh[(512 + j) * 256 + (k - 256)];
    Wg[i] = f2bf(v);
  }
  for (int i = tid; i < 1024; i += nth) {
    int g = (i >> 4) & 3, j = ((i >> 6) << 4) + (i & 15);
    float v;
    if (g == 0)      v = bih[j] + bhh[j];
    else if (g == 1) v = bih[256 + j] + bhh[256 + j];
    else if (g == 2) v = bih[512 + j];
    else             v = bhh[512 + j];
    bg[i] = v;
  }
}

// ---------------- x fp32 -> bf16 (vectorized) ----------------
__global__ __launch_bounds__(256) void k_f2bf(const float* __restrict__ x,
                                              us* __restrict__ o, int n8) {
  int i = blockIdx.x * blockDim.x + threadIdx.x;
  if (i >= n8) return;
  const float4* p = (const float4*)x + (size_t)i * 2;
  float4 a = p[0], b = p[1];
  us8 r;
  r[0] = f2bf(a.x); r[1] = f2bf(a.y); r[2] = f2bf(a.z); r[3] = f2bf(a.w);
  r[4] = f2bf(b.x); r[5] = f2bf(b.y); r[6] = f2bf(b.z); r[7] = f2bf(b.w);
  *(us8*)(o + (size_t)i * 8) = r;
}

// ---------------- children-avg: nbr[m] = avg(h[children(m)]) (bf16) ------------
// Parent gather is FUSED into EPI1's gload_lds staging (per-lane source addr),
// so this kernel only produces the neighbor average.
__global__ __launch_bounds__(256)
void k_child(const us* __restrict__ h, const int* __restrict__ chd,
             const int* __restrict__ cnt, us* __restrict__ nbr) {
  int wid = (blockIdx.x * blockDim.x + threadIdx.x) >> 6;  // one wave per node
  int l = threadIdx.x & 63;
  int m = wid;                       // 0..MM-1
  int b = m >> 12;                   // N = 4096
  int c = cnt[m];
  float inv = 1.f / (float)c;
  const int* ch = chd + (size_t)m * CC;
  us4 cv[CC];
#pragma unroll
  for (int i = 0; i < CC; ++i) {
    int rowC = (b << 12) + ch[i];
    cv[i] = *((const us4*)(h + ((size_t)rowC << 8)) + l);
  }
  float a0 = 0.f, a1 = 0.f, a2 = 0.f, a3 = 0.f;
#pragma unroll
  for (int i = 0; i < CC; ++i) {
    float wgt = (i < c) ? 1.f : 0.f;
    a0 += wgt * bf2f(cv[i][0]); a1 += wgt * bf2f(cv[i][1]);
    a2 += wgt * bf2f(cv[i][2]); a3 += wgt * bf2f(cv[i][3]);
  }
  us4 nb;
  nb[0] = f2bf(a0 * inv); nb[1] = f2bf(a1 * inv);
  nb[2] = f2bf(a2 * inv); nb[3] = f2bf(a3 * inv);
  *((us4*)(nbr + ((size_t)m << 8)) + l) = nb;
}

// ---------------- MFMA K-step (256x256 tile) with compile-time j-mask ----------
// 8 waves as 2(M) x 4(N); per wave 128x64 output = acc[8][4].
template <int JM>
DEVI void mma8(const us* As, const us* Bs, int wr, int wc, int l,
               f32x4 (&acc)[8][4]) {
#pragma unroll
  for (int ks = 0; ks < 2; ++ks) {
    bf16x8 af[8], bfr[4];
#pragma unroll
    for (int i = 0; i < 8; ++i) {
      int row = wr * 128 + i * 16 + (l & 15);
      int kb = ((ks * 32 + (l >> 4) * 8) * 2) ^ ((row & 7) << 4);  // swizzled read
      af[i] = *(const bf16x8*)((const char*)As + row * 128 + kb);
    }
#pragma unroll
    for (int j = 0; j < 4; ++j)
      if (JM & (1 << j)) {
        int row = wc * 64 + j * 16 + (l & 15);
        int kb = ((ks * 32 + (l >> 4) * 8) * 2) ^ ((row & 7) << 4);
        bfr[j] = *(const bf16x8*)((const char*)Bs + row * 128 + kb);
      }
#pragma unroll
    for (int i = 0; i < 8; ++i)
#pragma unroll
      for (int j = 0; j < 4; ++j)
        if (JM & (1 << j))
          acc[i][j] = __builtin_amdgcn_mfma_f32_16x16x32_bf16(af[i], bfr[j], acc[i][j], 0, 0, 0);
  }
}

DEVI void raw_barrier() {
  __builtin_amdgcn_sched_barrier(0);
  __builtin_amdgcn_s_barrier();      // RAW barrier: no implicit vmcnt(0) drain
  __builtin_amdgcn_sched_barrier(0);
}

// ---------------- GEMM: C = A @ Bw^T (+bias), 256x256 tile, dbuf prefetch ------
// R10 core — BEST MEASURED (total 510 µs; EPI2 103 µs). R11-R14 post-mortems:
// deep prefetch (R11), EPI1+EPI2 fusion (R12/R13: 256-reg spill), A-resident
// single-barrier (R14: B-load latency serialization) ALL regressed. Keep this.
// K-loop: stage(t+1) -> s_waitcnt vmcnt(8) counted -> raw barrier -> MFMA ->
// raw barrier. Raw s_barrier (not __syncthreads) keeps prefetched loads in
// flight across barriers (measured R5->R6).
// GA: A0 rows gathered through par[] (gload_lds global src is per-lane).
// NOTE: never request >2 waves/SIMD — acc alone is 128 regs; at 4/SIMD the
// R2 experiment spilled: 2.4 GB/dispatch scratch traffic, 3x slowdown.
template <int EPI, int KTOT, int KSPLIT, int NT, bool GA>
__global__ __launch_bounds__(512, 2)
void k_gemm(const us* __restrict__ A0, const us* __restrict__ A1, int strideA,
            const us* __restrict__ Bw, const float* __restrict__ bias,
            us* __restrict__ outBf, float* __restrict__ outF,
            const float* __restrict__ sF, int writeF32,
            const int* __restrict__ par) {
  __shared__ __align__(16) us As[2][256 * 64];
  __shared__ __align__(16) us Bs[2][256 * 64];
  int tid = threadIdx.x;
  int w = tid >> 6, l = tid & 63;
  int wr = w >> 2, wc = w & 3;
  int bid = blockIdx.x;
  int per = gridDim.x >> 3;
  int g = (bid & 7) * per + (bid >> 3);
  int mi, ni;
  if (NT == 1) { mi = g; ni = 0; }
  else         { mi = g / NT; ni = g - mi * NT; }
  int mBase = mi * 256, nBase = ni * 256;
  f32x4 acc[8][4] = {};

  // parent-gathered row index per staging row (GA only)
  int prow[4];
  if (GA) {
    int bb = (mBase >> 12) << 12;
#pragma unroll
    for (int c = 0; c < 4; ++c)
      prow[c] = bb + par[mBase + c * 64 + (tid >> 3)];
  }

  auto stage = [&](int t) {
    int kt = t * 64, buf = t & 1;
    const us* aSrc; int kOff;
    if (kt < KSPLIT) { aSrc = A0; kOff = kt; }
    else             { aSrc = A1; kOff = kt - KSPLIT; }
#pragma unroll
    for (int c = 0; c < 4; ++c) {
      int row = c * 64 + (tid >> 3);
      int kb = ((tid & 7) * 16) ^ ((row & 7) << 4);   // pre-swizzled global source
      const char* ga;
      if (GA && kt < KSPLIT)
        ga = (const char*)(aSrc + (size_t)prow[c] * strideA + kOff) + kb;
      else
        ga = (const char*)(aSrc + (size_t)(mBase + row) * strideA + kOff) + kb;
      gload_lds16(ga, (char*)As[buf] + row * 128 + (tid & 7) * 16);
      const char* gb = (const char*)(Bw + (size_t)(nBase + row) * KTOT + kt) + kb;
      gload_lds16(gb, (char*)Bs[buf] + row * 128 + (tid & 7) * 16);
    }
  };

  constexpr int NKT = KTOT / 64;
  stage(0);
#pragma unroll
  for (int t = 0; t < NKT; ++t) {
    if (t + 1 < NKT) {
      stage(t + 1);
      asm volatile("s_waitcnt vmcnt(8)" ::: "memory");  // tile t done; t+1 in flight
    } else {
      asm volatile("s_waitcnt vmcnt(0)" ::: "memory");
    }
    raw_barrier();                     // LDS tile-t writes visible to all waves
    int buf = t & 1;
    if (EPI == 2) {
      if (t * 64 < KSPLIT) mma8<0b0111>(As[buf], Bs[buf], wr, wc, l, acc);  // skip hn
      else                 mma8<0b1011>(As[buf], Bs[buf], wr, wc, l, acc);  // skip xn
    } else {
      mma8<0b1111>(As[buf], Bs[buf], wr, wc, l, acc);
    }
    raw_barrier();                     // all reads of buf done before restage
  }

  int rBase0 = mBase + wr * 128;
  int cBase0 = nBase + wc * 64;
  if (EPI == 0 || EPI == 1) {
#pragma unroll
    for (int i = 0; i < 8; ++i)
#pragma unroll
      for (int j = 0; j < 4; ++j) {
        int col = cBase0 + j * 16 + (l & 15);
        int row0 = rBase0 + i * 16 + ((l >> 4) << 2);
        float bb = bias[col];
#pragma unroll
        for (int e = 0; e < 4; ++e) {
          float v = acc[i][j][e] + bb;
          size_t off = (size_t)(row0 + e) * 256 + col;
          outBf[off] = f2bf(v);
          if (EPI == 1) outF[off] = v;
        }
      }
  } else {
    // shuffle-free: j-fragment == gate (wave spans 64 gate-cols = 16 out cols)
    int outCol = ((nBase >> 6) + wc) * 16 + (l & 15);
    float b0 = bias[cBase0 + 0  + (l & 15)];
    float b1 = bias[cBase0 + 16 + (l & 15)];
    float b2 = bias[cBase0 + 32 + (l & 15)];
    float b3 = bias[cBase0 + 48 + (l & 15)];
#pragma unroll
    for (int i = 0; i < 8; ++i) {
      int row0 = rBase0 + i * 16 + ((l >> 4) << 2);
#pragma unroll
      for (int e = 0; e < 4; ++e) {
        float r = sigf(acc[i][0][e] + b0);
        float z = sigf(acc[i][1][e] + b1);
        float n = tanhfast(acc[i][2][e] + b2 + r * (acc[i][3][e] + b3));
        size_t off = (size_t)(row0 + e) * 256 + outCol;
        float sv = sF[off];
        float o = (1.f - z) * n + z * sv;
        if (writeF32) outF[off] = o;
        else          outBf[off] = f2bf(o);
      }
    }
  }
}

extern "C" void kernel_launch(void* const* d_in, const int* in_sizes, int n_in,
                              void* d_out, int out_size, void* d_ws, size_t ws_size,
                              hipStream_t stream) {
  const float* x    = (const float*)d_in[0];
  const int*   par  = (const int*)d_in[1];
  const int*   chd  = (const int*)d_in[2];
  const int*   cnt  = (const int*)d_in[3];
  const float* Wres = (const float*)d_in[4];
  const float* bres = (const float*)d_in[5];
  const float* Wpar = (const float*)d_in[6];
  const float* bpar = (const float*)d_in[7];
  const float* Wnbr = (const float*)d_in[8];
  const float* bnbr = (const float*)d_in[9];
  const float* Wih  = (const float*)d_in[10];
  const float* Whh  = (const float*)d_in[11];
  const float* bih  = (const float*)d_in[12];
  const float* bhh  = (const float*)d_in[13];

  char* ws = (char*)d_ws;
  size_t off = 0;
  auto alloc = [&](size_t sz) { char* p = ws + off; off += (sz + 255) & ~(size_t)255; return p; };
  us*    Wg   = (us*)alloc((size_t)1024 * 512 * 2);
  us*    Wcat = (us*)alloc((size_t)256 * 512 * 2);
  us*    Wr   = (us*)alloc((size_t)256 * 256 * 2);
  float* bcat = (float*)alloc(256 * 4);
  float* bg   = (float*)alloc(1024 * 4);
  us*    xbf  = (us*)alloc((size_t)MM * 256 * 2);  // reused as s_bf after resize
  us*    h0   = (us*)alloc((size_t)MM * 256 * 2);
  us*    h1   = (us*)alloc((size_t)MM * 256 * 2);
  us*    nbr  = (us*)alloc((size_t)MM * 256 * 2);
  us*    sbf  = xbf;
  float* sF   = (float*)d_out;  // f32 s scratch lives in d_out (final iter
                                // overwrites each slot after its own sv read)

  k_prep<<<256, 256, 0, stream>>>(Wres, Wpar, bpar, Wnbr, bnbr, Wih, Whh, bih, bhh,
                                  Wr, Wcat, bcat, Wg, bg);
  k_f2bf<<<(MM * 256 / 8) / 256, 256, 0, stream>>>(x, xbf, MM * 256 / 8);

  // h0 = x @ W_resize^T + b_resize   (M/256 = 256 blocks, single n-tile)
  k_gemm<0, 256, 256, 1, false><<<256, 512, 0, stream>>>(
      xbf, xbf, 256, Wr, bres, h0, nullptr, nullptr, 0, nullptr);

  us* hc = h0;
  for (int it = 0; it < 3; ++it) {
    us* hn = (hc == h0) ? h1 : h0;
    k_child<<<MM / 4, 256, 0, stream>>>(hc, chd, cnt, nbr);
    // s = [h[par] | nbr] @ Wcat^T + bcat  (parent gather fused into staging)
    k_gemm<1, 512, 256, 1, true><<<256, 512, 0, stream>>>(
        hc, nbr, 256, Wcat, bcat, sbf, sF, nullptr, 0, par);
    // fused GRU: [h|s] @ Wg^T, gate epilogue -> h_next (bf16) or d_out (f32, last)
    k_gemm<2, 512, 256, 4, false><<<1024, 512, 0, stream>>>(
        hc, sbf, 256, Wg, bg, hn, (float*)d_out, sF, (it == 2) ? 1 : 0, nullptr);
    hc = hn;
  }
}

// Round 16
// 485.911 us; speedup vs baseline: 1.6286x; 1.0463x over previous
//
#include <hip/hip_runtime.h>

typedef unsigned short us;
typedef us us4 __attribute__((ext_vector_type(4)));
typedef us us8 __attribute__((ext_vector_type(8)));
typedef short bf16x8 __attribute__((ext_vector_type(8)));
typedef float f32x4 __attribute__((ext_vector_type(4)));

#define DEVI static __device__ __forceinline__

// constants for this problem instance
#define BB 16
#define NN 4096
#define PP 256
#define CC 8
#define MM (BB * NN)   // 65536

DEVI float bf2f(us u) { unsigned x = ((unsigned)u) << 16; return __builtin_bit_cast(float, x); }
DEVI us f2bf(float f) {
  unsigned x = __builtin_bit_cast(unsigned, f);
  x += 0x7fffu + ((x >> 16) & 1u);   // round to nearest even
  return (us)(x >> 16);
}

DEVI void gload_lds16(const void* g, void* l) {
  __builtin_amdgcn_global_load_lds(
      (const __attribute__((address_space(1))) void*)g,
      (__attribute__((address_space(3))) void*)l, 16, 0, 0);
}

DEVI float sigf(float x) { return 1.f / (1.f + __expf(-x)); }
DEVI float tanhfast(float a) {
  float aa = fabsf(a);
  float t = 1.f - 2.f / (1.f + __expf(2.f * aa));
  return copysignf(t, a);
}

DEVI void raw_barrier() {
  __builtin_amdgcn_sched_barrier(0);
  __builtin_amdgcn_s_barrier();      // RAW barrier: no implicit vmcnt(0) drain
  __builtin_amdgcn_sched_barrier(0);
}

// ---------------- weight prep ---------------------------------------------------
// Wcat[256][512] = [W_parent | W_nbr]; bcat = bpar + bnbr.
// Packed gates weights (192-row B-tiles, no dead rows):
//   Wgh[768][256] (h-half, from Wih) / Wgs[768][256] (s-half, from Whh):
//   row R -> J16 = R/48, slot = (R/16)%3, c = R%15..: j_out = J16*16 + (R&15);
//   slot 0 = r-gate row, slot 1 = z-gate row, slot 2 = n-gate row (xn / hn).
// bg stays in the old 1024 gate-interleaved layout (16-col groups x 4 gates).
__global__ void k_prep(const float* __restrict__ Wres,
                       const float* __restrict__ Wpar, const float* __restrict__ bpar,
                       const float* __restrict__ Wnbr, const float* __restrict__ bnbr,
                       const float* __restrict__ Wih, const float* __restrict__ Whh,
                       const float* __restrict__ bih, const float* __restrict__ bhh,
                       us* __restrict__ Wr, us* __restrict__ Wcat, float* __restrict__ bcat,
                       us* __restrict__ Wgh, us* __restrict__ Wgs, float* __restrict__ bg) {
  int tid = blockIdx.x * blockDim.x + threadIdx.x;
  int nth = gridDim.x * blockDim.x;
  for (int i = tid; i < 256 * 256; i += nth) Wr[i] = f2bf(Wres[i]);
  for (int i = tid; i < 256 * 512; i += nth) {
    int o = i >> 9, k = i & 511;
    float v = (k < 256) ? Wpar[o * 256 + k] : Wnbr[o * 256 + (k - 256)];
    Wcat[i] = f2bf(v);
  }
  for (int i = tid; i < 256; i += nth) bcat[i] = bpar[i] + bnbr[i];
  for (int i = tid; i < 768 * 256; i += nth) {
    int R = i >> 8, k = i & 255;
    int j = (R / 48) * 16 + (R & 15);
    int slot = (R >> 4) % 3;                     // 0=r 1=z 2=n
    Wgh[i] = f2bf(Wih[(size_t)(slot * 256 + j) * 256 + k]);
    Wgs[i] = f2bf(Whh[(size_t)(slot * 256 + j) * 256 + k]);
  }
  for (int i = tid; i < 1024; i += nth) {
    int g = (i >> 4) & 3, j = ((i >> 6) << 4) + (i & 15);
    float v;
    if (g == 0)      v = bih[j] + bhh[j];
    else if (g == 1) v = bih[256 + j] + bhh[256 + j];
    else if (g == 2) v = bih[512 + j];
    else             v = bhh[512 + j];
    bg[i] = v;
  }
}

// ---------------- x fp32 -> bf16 (vectorized) ----------------
__global__ __launch_bounds__(256) void k_f2bf(const float* __restrict__ x,
                                              us* __restrict__ o, int n8) {
  int i = blockIdx.x * blockDim.x + threadIdx.x;
  if (i >= n8) return;
  const float4* p = (const float4*)x + (size_t)i * 2;
  float4 a = p[0], b = p[1];
  us8 r;
  r[0] = f2bf(a.x); r[1] = f2bf(a.y); r[2] = f2bf(a.z); r[3] = f2bf(a.w);
  r[4] = f2bf(b.x); r[5] = f2bf(b.y); r[6] = f2bf(b.z); r[7] = f2bf(b.w);
  *(us8*)(o + (size_t)i * 8) = r;
}

// ---------------- children-avg: nbr[m] = avg(h[children(m)]) (bf16) ------------
__global__ __launch_bounds__(256)
void k_child(const us* __restrict__ h, const int* __restrict__ chd,
             const int* __restrict__ cnt, us* __restrict__ nbr) {
  int wid = (blockIdx.x * blockDim.x + threadIdx.x) >> 6;  // one wave per node
  int l = threadIdx.x & 63;
  int m = wid;                       // 0..MM-1
  int b = m >> 12;                   // N = 4096
  int c = cnt[m];
  float inv = 1.f / (float)c;
  const int* ch = chd + (size_t)m * CC;
  us4 cv[CC];
#pragma unroll
  for (int i = 0; i < CC; ++i) {
    int rowC = (b << 12) + ch[i];
    cv[i] = *((const us4*)(h + ((size_t)rowC << 8)) + l);
  }
  float a0 = 0.f, a1 = 0.f, a2 = 0.f, a3 = 0.f;
#pragma unroll
  for (int i = 0; i < CC; ++i) {
    float wgt = (i < c) ? 1.f : 0.f;
    a0 += wgt * bf2f(cv[i][0]); a1 += wgt * bf2f(cv[i][1]);
    a2 += wgt * bf2f(cv[i][2]); a3 += wgt * bf2f(cv[i][3]);
  }
  us4 nb;
  nb[0] = f2bf(a0 * inv); nb[1] = f2bf(a1 * inv);
  nb[2] = f2bf(a2 * inv); nb[3] = f2bf(a3 * inv);
  *((us4*)(nbr + ((size_t)m << 8)) + l) = nb;
}

// ---------------- MFMA K-step (256x256 tile), full 4-j (EPI0/EPI1) -------------
DEVI void mma8(const us* As, const us* Bs, int wr, int wc, int l,
               f32x4 (&acc)[8][4]) {
#pragma unroll
  for (int ks = 0; ks < 2; ++ks) {
    bf16x8 af[8], bfr[4];
#pragma unroll
    for (int i = 0; i < 8; ++i) {
      int row = wr * 128 + i * 16 + (l & 15);
      int kb = ((ks * 32 + (l >> 4) * 8) * 2) ^ ((row & 7) << 4);  // swizzled read
      af[i] = *(const bf16x8*)((const char*)As + row * 128 + kb);
    }
#pragma unroll
    for (int j = 0; j < 4; ++j) {
      int row = wc * 64 + j * 16 + (l & 15);
      int kb = ((ks * 32 + (l >> 4) * 8) * 2) ^ ((row & 7) << 4);
      bfr[j] = *(const bf16x8*)((const char*)Bs + row * 128 + kb);
    }
#pragma unroll
    for (int i = 0; i < 8; ++i)
#pragma unroll
      for (int j = 0; j < 4; ++j)
        acc[i][j] = __builtin_amdgcn_mfma_f32_16x16x32_bf16(af[i], bfr[j], acc[i][j], 0, 0, 0);
  }
}

// ---------------- MFMA K-step, 192-row packed B (gates) ------------------------
// 3 j-fragments per k-tile; slot 2 accumulates into acc[.][2] (xn) on the
// h-half (HN=0) and acc[.][3] (hn) on the s-half (HN=1).
template <int HN>
DEVI void mma8g(const us* As, const us* Bs, int wr, int wc, int l,
                f32x4 (&acc)[8][4]) {
#pragma unroll
  for (int ks = 0; ks < 2; ++ks) {
    bf16x8 af[8], bfr[3];
#pragma unroll
    for (int i = 0; i < 8; ++i) {
      int row = wr * 128 + i * 16 + (l & 15);
      int kb = ((ks * 32 + (l >> 4) * 8) * 2) ^ ((row & 7) << 4);
      af[i] = *(const bf16x8*)((const char*)As + row * 128 + kb);
    }
#pragma unroll
    for (int j = 0; j < 3; ++j) {
      int row = wc * 48 + j * 16 + (l & 15);
      int kb = ((ks * 32 + (l >> 4) * 8) * 2) ^ ((row & 7) << 4);
      bfr[j] = *(const bf16x8*)((const char*)Bs + row * 128 + kb);
    }
#pragma unroll
    for (int i = 0; i < 8; ++i)
#pragma unroll
      for (int j = 0; j < 3; ++j) {
        int aj = (j < 2) ? j : (HN ? 3 : 2);
        acc[i][aj] = __builtin_amdgcn_mfma_f32_16x16x32_bf16(af[i], bfr[j], acc[i][aj], 0, 0, 0);
      }
  }
}

// ---------------- GEMM: C = A @ Bw^T (+bias), 256x256 tile (EPI0/EPI1) ---------
// R10 core — best measured. K-loop: stage(t+1) -> vmcnt(8) counted -> raw
// barrier -> MFMA -> raw barrier. GA: A0 rows gathered through par[].
// NOTE: never request >2 waves/SIMD — acc alone is 128 regs (R2: spill, 3x).
template <int EPI, int KTOT, int KSPLIT, bool GA>
__global__ __launch_bounds__(512, 2)
void k_gemm(const us* __restrict__ A0, const us* __restrict__ A1, int strideA,
            const us* __restrict__ Bw, const float* __restrict__ bias,
            us* __restrict__ outBf, float* __restrict__ outF, int writeF32,
            const int* __restrict__ par) {
  __shared__ __align__(16) us As[2][256 * 64];
  __shared__ __align__(16) us Bs[2][256 * 64];
  int tid = threadIdx.x;
  int w = tid >> 6, l = tid & 63;
  int wr = w >> 2, wc = w & 3;
  int bid = blockIdx.x;
  int per = gridDim.x >> 3;
  int mi = (bid & 7) * per + (bid >> 3);   // XCD-chunked, single n-tile
  int mBase = mi * 256;
  f32x4 acc[8][4] = {};

  int prow[4];
  if (GA) {
    int bb = (mBase >> 12) << 12;
#pragma unroll
    for (int c = 0; c < 4; ++c)
      prow[c] = bb + par[mBase + c * 64 + (tid >> 3)];
  }

  auto stage = [&](int t) {
    int kt = t * 64, buf = t & 1;
    const us* aSrc; int kOff;
    if (kt < KSPLIT) { aSrc = A0; kOff = kt; }
    else             { aSrc = A1; kOff = kt - KSPLIT; }
#pragma unroll
    for (int c = 0; c < 4; ++c) {
      int row = c * 64 + (tid >> 3);
      int kb = ((tid & 7) * 16) ^ ((row & 7) << 4);   // pre-swizzled global source
      const char* ga;
      if (GA && kt < KSPLIT)
        ga = (const char*)(aSrc + (size_t)prow[c] * strideA + kOff) + kb;
      else
        ga = (const char*)(aSrc + (size_t)(mBase + row) * strideA + kOff) + kb;
      gload_lds16(ga, (char*)As[buf] + row * 128 + (tid & 7) * 16);
      const char* gb = (const char*)(Bw + (size_t)row * KTOT + kt) + kb;
      gload_lds16(gb, (char*)Bs[buf] + row * 128 + (tid & 7) * 16);
    }
  };

  constexpr int NKT = KTOT / 64;
  stage(0);
#pragma unroll
  for (int t = 0; t < NKT; ++t) {
    if (t + 1 < NKT) {
      stage(t + 1);
      asm volatile("s_waitcnt vmcnt(8)" ::: "memory");  // tile t done; t+1 in flight
    } else {
      asm volatile("s_waitcnt vmcnt(0)" ::: "memory");
    }
    raw_barrier();
    mma8(As[t & 1], Bs[t & 1], wr, wc, l, acc);
    raw_barrier();
  }

  int rBase0 = mBase + wr * 128;
  int cBase0 = wc * 64;
#pragma unroll
  for (int i = 0; i < 8; ++i)
#pragma unroll
    for (int j = 0; j < 4; ++j) {
      int col = cBase0 + j * 16 + (l & 15);
      int row0 = rBase0 + i * 16 + ((l >> 4) << 2);
      float bb = bias[col];
#pragma unroll
      for (int e = 0; e < 4; ++e) {
        float v = acc[i][j][e] + bb;
        size_t off = (size_t)(row0 + e) * 256 + col;
        outBf[off] = f2bf(v);
        if (EPI == 1 && writeF32) outF[off] = v;
      }
    }
}

// ---------------- gates GEMM: [h|s] @ packed-Wg, fused GRU epilogue ------------
// 192-row B-tiles (zero dead rows): Bs 2x24 KB, 7 loads/thread/stage -> vmcnt(7).
// sv source: it<2 -> bf16 sbf (saves the f32 sF round-trip, ~96 MB/iter);
// final it -> exact f32 sF (d_out precision preserved).
__global__ __launch_bounds__(512, 2)
void k_gates(const us* __restrict__ h, const us* __restrict__ s,
             const us* __restrict__ Wgh, const us* __restrict__ Wgs,
             const float* __restrict__ bg,
             us* __restrict__ outBf, float* __restrict__ outF,
             const us* __restrict__ svBf, const float* __restrict__ sF,
             int finalIt) {
  __shared__ __align__(16) us As[2][256 * 64];   // 64 KB
  __shared__ __align__(16) us Bs[2][192 * 64];   // 48 KB
  int tid = threadIdx.x;
  int w = tid >> 6, l = tid & 63;
  int wr = w >> 2, wc = w & 3;
  int bid = blockIdx.x;
  int per = gridDim.x >> 3;
  int g = (bid & 7) * per + (bid >> 3);
  int mi = g >> 2, ni = g & 3;                   // NT=4
  int mBase = mi * 256, nB = ni * 192, nBase = ni * 256;
  f32x4 acc[8][4] = {};

  auto stage = [&](int t) {
    int buf = t & 1;
    const us* aSrc = (t < 4) ? h : s;
    const us* bSrc = (t < 4) ? Wgh : Wgs;
    int kOff = (t & 3) * 64;
#pragma unroll
    for (int c = 0; c < 4; ++c) {
      int row = c * 64 + (tid >> 3);
      int kb = ((tid & 7) * 16) ^ ((row & 7) << 4);
      gload_lds16((const char*)(aSrc + (size_t)(mBase + row) * 256 + kOff) + kb,
                  (char*)As[buf] + row * 128 + (tid & 7) * 16);
    }
#pragma unroll
    for (int c = 0; c < 3; ++c) {
      int row = c * 64 + (tid >> 3);
      int kb = ((tid & 7) * 16) ^ ((row & 7) << 4);
      gload_lds16((const char*)(bSrc + (size_t)(nB + row) * 256 + kOff) + kb,
                  (char*)Bs[buf] + row * 128 + (tid & 7) * 16);
    }
  };

  stage(0);
#pragma unroll
  for (int t = 0; t < 8; ++t) {
    if (t + 1 < 8) {
      stage(t + 1);
      asm volatile("s_waitcnt vmcnt(7)" ::: "memory");  // tile t's 7 done; t+1 in flight
    } else {
      asm volatile("s_waitcnt vmcnt(0)" ::: "memory");
    }
    raw_barrier();
    if (t < 4) mma8g<0>(As[t & 1], Bs[t & 1], wr, wc, l, acc);  // slot2 -> xn
    else       mma8g<1>(As[t & 1], Bs[t & 1], wr, wc, l, acc);  // slot2 -> hn
    raw_barrier();
  }

  // shuffle-free GRU epilogue: acc j == gate {r, z, xn, hn}
  int rBase0 = mBase + wr * 128;
  int cB = nBase + wc * 64;
  int outCol = ((nBase >> 6) + wc) * 16 + (l & 15);
  float b0 = bg[cB + 0  + (l & 15)];
  float b1 = bg[cB + 16 + (l & 15)];
  float b2 = bg[cB + 32 + (l & 15)];
  float b3 = bg[cB + 48 + (l & 15)];
#pragma unroll
  for (int i = 0; i < 8; ++i) {
    int row0 = rBase0 + i * 16 + ((l >> 4) << 2);
#pragma unroll
    for (int e = 0; e < 4; ++e) {
      float r = sigf(acc[i][0][e] + b0);
      float z = sigf(acc[i][1][e] + b1);
      float n = tanhfast(acc[i][2][e] + b2 + r * (acc[i][3][e] + b3));
      size_t off = (size_t)(row0 + e) * 256 + outCol;
      float sv = finalIt ? sF[off] : bf2f(svBf[off]);
      float o = (1.f - z) * n + z * sv;
      if (finalIt) outF[off] = o;
      else         outBf[off] = f2bf(o);
    }
  }
}

extern "C" void kernel_launch(void* const* d_in, const int* in_sizes, int n_in,
                              void* d_out, int out_size, void* d_ws, size_t ws_size,
                              hipStream_t stream) {
  const float* x    = (const float*)d_in[0];
  const int*   par  = (const int*)d_in[1];
  const int*   chd  = (const int*)d_in[2];
  const int*   cnt  = (const int*)d_in[3];
  const float* Wres = (const float*)d_in[4];
  const float* bres = (const float*)d_in[5];
  const float* Wpar = (const float*)d_in[6];
  const float* bpar = (const float*)d_in[7];
  const float* Wnbr = (const float*)d_in[8];
  const float* bnbr = (const float*)d_in[9];
  const float* Wih  = (const float*)d_in[10];
  const float* Whh  = (const float*)d_in[11];
  const float* bih  = (const float*)d_in[12];
  const float* bhh  = (const float*)d_in[13];

  char* ws = (char*)d_ws;
  size_t off = 0;
  auto alloc = [&](size_t sz) { char* p = ws + off; off += (sz + 255) & ~(size_t)255; return p; };
  us*    Wgh  = (us*)alloc((size_t)768 * 256 * 2);
  us*    Wgs  = (us*)alloc((size_t)768 * 256 * 2);
  us*    Wcat = (us*)alloc((size_t)256 * 512 * 2);
  us*    Wr   = (us*)alloc((size_t)256 * 256 * 2);
  float* bcat = (float*)alloc(256 * 4);
  float* bg   = (float*)alloc(1024 * 4);
  us*    xbf  = (us*)alloc((size_t)MM * 256 * 2);  // reused as s_bf after resize
  us*    h0   = (us*)alloc((size_t)MM * 256 * 2);
  us*    h1   = (us*)alloc((size_t)MM * 256 * 2);
  us*    nbr  = (us*)alloc((size_t)MM * 256 * 2);
  us*    sbf  = xbf;
  float* sF   = (float*)d_out;  // f32 s scratch in d_out (final iter only;
                                // each slot overwritten after its own sv read)

  k_prep<<<256, 256, 0, stream>>>(Wres, Wpar, bpar, Wnbr, bnbr, Wih, Whh, bih, bhh,
                                  Wr, Wcat, bcat, Wgh, Wgs, bg);
  k_f2bf<<<(MM * 256 / 8) / 256, 256, 0, stream>>>(x, xbf, MM * 256 / 8);

  // h0 = x @ W_resize^T + b_resize   (M/256 = 256 blocks, single n-tile)
  k_gemm<0, 256, 256, false><<<256, 512, 0, stream>>>(
      xbf, xbf, 256, Wr, bres, h0, nullptr, 0, nullptr);

  us* hc = h0;
  for (int it = 0; it < 3; ++it) {
    us* hn = (hc == h0) ? h1 : h0;
    k_child<<<MM / 4, 256, 0, stream>>>(hc, chd, cnt, nbr);
    // s = [h[par] | nbr] @ Wcat^T + bcat  (parent gather fused into staging;
    // f32 sF written only on the final iteration)
    k_gemm<1, 512, 256, true><<<256, 512, 0, stream>>>(
        hc, nbr, 256, Wcat, bcat, sbf, sF, (it == 2) ? 1 : 0, par);
    // gates = [h|s] @ packed-Wg, fused GRU -> h_next (bf16) or d_out (f32)
    k_gates<<<1024, 512, 0, stream>>>(
        hc, sbf, Wgh, Wgs, bg, hn, (float*)d_out, sbf, sF, (it == 2) ? 1 : 0);
    hc = hn;
  }
}

// Round 17
// 483.903 us; speedup vs baseline: 1.6354x; 1.0041x over previous
//
#include <hip/hip_runtime.h>

typedef unsigned short us;
typedef us us4 __attribute__((ext_vector_type(4)));
typedef us us8 __attribute__((ext_vector_type(8)));
typedef short bf16x8 __attribute__((ext_vector_type(8)));
typedef float f32x4 __attribute__((ext_vector_type(4)));

#define DEVI static __device__ __forceinline__

// constants for this problem instance
#define BB 16
#define NN 4096
#define PP 256
#define CC 8
#define MM (BB * NN)   // 65536

DEVI float bf2f(us u) { unsigned x = ((unsigned)u) << 16; return __builtin_bit_cast(float, x); }
DEVI us f2bf(float f) {
  unsigned x = __builtin_bit_cast(unsigned, f);
  x += 0x7fffu + ((x >> 16) & 1u);   // round to nearest even
  return (us)(x >> 16);
}

DEVI void gload_lds16(const void* g, void* l) {
  __builtin_amdgcn_global_load_lds(
      (const __attribute__((address_space(1))) void*)g,
      (__attribute__((address_space(3))) void*)l, 16, 0, 0);
}

DEVI float sigf(float x) { return 1.f / (1.f + __expf(-x)); }
DEVI float tanhfast(float a) {
  float aa = fabsf(a);
  float t = 1.f - 2.f / (1.f + __expf(2.f * aa));
  return copysignf(t, a);
}

DEVI void raw_barrier() {
  __builtin_amdgcn_sched_barrier(0);
  __builtin_amdgcn_s_barrier();      // RAW barrier: no implicit vmcnt(0) drain
  __builtin_amdgcn_sched_barrier(0);
}

// ---------------- weight prep ---------------------------------------------------
// Wcat[256][512] = [W_parent | W_nbr]; bcat = bpar + bnbr.
// Packed gates weights (192-row B-tiles, no dead rows):
//   Wgh[768][256] (h-half, from Wih) / Wgs[768][256] (s-half, from Whh):
//   row R -> J16 = R/48, slot = (R/16)%3; j_out = J16*16 + (R&15);
//   slot 0 = r-gate row, slot 1 = z-gate row, slot 2 = n-gate row (xn / hn).
// bg stays in the 1024 gate-interleaved layout (16-col groups x 4 gates).
__global__ void k_prep(const float* __restrict__ Wres,
                       const float* __restrict__ Wpar, const float* __restrict__ bpar,
                       const float* __restrict__ Wnbr, const float* __restrict__ bnbr,
                       const float* __restrict__ Wih, const float* __restrict__ Whh,
                       const float* __restrict__ bih, const float* __restrict__ bhh,
                       us* __restrict__ Wr, us* __restrict__ Wcat, float* __restrict__ bcat,
                       us* __restrict__ Wgh, us* __restrict__ Wgs, float* __restrict__ bg) {
  int tid = blockIdx.x * blockDim.x + threadIdx.x;
  int nth = gridDim.x * blockDim.x;
  for (int i = tid; i < 256 * 256; i += nth) Wr[i] = f2bf(Wres[i]);
  for (int i = tid; i < 256 * 512; i += nth) {
    int o = i >> 9, k = i & 511;
    float v = (k < 256) ? Wpar[o * 256 + k] : Wnbr[o * 256 + (k - 256)];
    Wcat[i] = f2bf(v);
  }
  for (int i = tid; i < 256; i += nth) bcat[i] = bpar[i] + bnbr[i];
  for (int i = tid; i < 768 * 256; i += nth) {
    int R = i >> 8, k = i & 255;
    int j = (R / 48) * 16 + (R & 15);
    int slot = (R >> 4) % 3;                     // 0=r 1=z 2=n
    Wgh[i] = f2bf(Wih[(size_t)(slot * 256 + j) * 256 + k]);
    Wgs[i] = f2bf(Whh[(size_t)(slot * 256 + j) * 256 + k]);
  }
  for (int i = tid; i < 1024; i += nth) {
    int g = (i >> 4) & 3, j = ((i >> 6) << 4) + (i & 15);
    float v;
    if (g == 0)      v = bih[j] + bhh[j];
    else if (g == 1) v = bih[256 + j] + bhh[256 + j];
    else if (g == 2) v = bih[512 + j];
    else             v = bhh[512 + j];
    bg[i] = v;
  }
}

// ---------------- x fp32 -> bf16 (vectorized) ----------------
__global__ __launch_bounds__(256) void k_f2bf(const float* __restrict__ x,
                                              us* __restrict__ o, int n8) {
  int i = blockIdx.x * blockDim.x + threadIdx.x;
  if (i >= n8) return;
  const float4* p = (const float4*)x + (size_t)i * 2;
  float4 a = p[0], b = p[1];
  us8 r;
  r[0] = f2bf(a.x); r[1] = f2bf(a.y); r[2] = f2bf(a.z); r[3] = f2bf(a.w);
  r[4] = f2bf(b.x); r[5] = f2bf(b.y); r[6] = f2bf(b.z); r[7] = f2bf(b.w);
  *(us8*)(o + (size_t)i * 8) = r;
}

// ---------------- children-avg: nbr[m] = avg(h[children(m)]) (bf16) ------------
__global__ __launch_bounds__(256)
void k_child(const us* __restrict__ h, const int* __restrict__ chd,
             const int* __restrict__ cnt, us* __restrict__ nbr) {
  int wid = (blockIdx.x * blockDim.x + threadIdx.x) >> 6;  // one wave per node
  int l = threadIdx.x & 63;
  int m = wid;                       // 0..MM-1
  int b = m >> 12;                   // N = 4096
  int c = cnt[m];
  float inv = 1.f / (float)c;
  const int* ch = chd + (size_t)m * CC;
  us4 cv[CC];
#pragma unroll
  for (int i = 0; i < CC; ++i) {
    int rowC = (b << 12) + ch[i];
    cv[i] = *((const us4*)(h + ((size_t)rowC << 8)) + l);
  }
  float a0 = 0.f, a1 = 0.f, a2 = 0.f, a3 = 0.f;
#pragma unroll
  for (int i = 0; i < CC; ++i) {
    float wgt = (i < c) ? 1.f : 0.f;
    a0 += wgt * bf2f(cv[i][0]); a1 += wgt * bf2f(cv[i][1]);
    a2 += wgt * bf2f(cv[i][2]); a3 += wgt * bf2f(cv[i][3]);
  }
  us4 nb;
  nb[0] = f2bf(a0 * inv); nb[1] = f2bf(a1 * inv);
  nb[2] = f2bf(a2 * inv); nb[3] = f2bf(a3 * inv);
  *((us4*)(nbr + ((size_t)m << 8)) + l) = nb;
}

// ---------------- MFMA K-step (256x256 tile), full 4-j (EPI0/EPI1) -------------
DEVI void mma8(const us* As, const us* Bs, int wr, int wc, int l,
               f32x4 (&acc)[8][4]) {
#pragma unroll
  for (int ks = 0; ks < 2; ++ks) {
    bf16x8 af[8], bfr[4];
#pragma unroll
    for (int i = 0; i < 8; ++i) {
      int row = wr * 128 + i * 16 + (l & 15);
      int kb = ((ks * 32 + (l >> 4) * 8) * 2) ^ ((row & 7) << 4);  // swizzled read
      af[i] = *(const bf16x8*)((const char*)As + row * 128 + kb);
    }
#pragma unroll
    for (int j = 0; j < 4; ++j) {
      int row = wc * 64 + j * 16 + (l & 15);
      int kb = ((ks * 32 + (l >> 4) * 8) * 2) ^ ((row & 7) << 4);
      bfr[j] = *(const bf16x8*)((const char*)Bs + row * 128 + kb);
    }
#pragma unroll
    for (int i = 0; i < 8; ++i)
#pragma unroll
      for (int j = 0; j < 4; ++j)
        acc[i][j] = __builtin_amdgcn_mfma_f32_16x16x32_bf16(af[i], bfr[j], acc[i][j], 0, 0, 0);
  }
}

// ---------------- MFMA phase (gates): one ks-subset, 192-row packed B ----------
// slot 2 accumulates into acc[.][2] (xn) on the h-half (HN=0) and acc[.][3]
// (hn) on the s-half (HN=1). setprio(1) around the MFMA cluster (T5) —
// phase-split role diversity makes the CU scheduler favor MFMA-entering waves.
template <int HN, int KS>
DEVI void mma8g_ks(const us* As, const us* Bs, int wr, int wc, int l,
                   f32x4 (&acc)[8][4]) {
  bf16x8 af[8], bfr[3];
#pragma unroll
  for (int i = 0; i < 8; ++i) {
    int row = wr * 128 + i * 16 + (l & 15);
    int kb = ((KS * 32 + (l >> 4) * 8) * 2) ^ ((row & 7) << 4);
    af[i] = *(const bf16x8*)((const char*)As + row * 128 + kb);
  }
#pragma unroll
  for (int j = 0; j < 3; ++j) {
    int row = wc * 48 + j * 16 + (l & 15);
    int kb = ((KS * 32 + (l >> 4) * 8) * 2) ^ ((row & 7) << 4);
    bfr[j] = *(const bf16x8*)((const char*)Bs + row * 128 + kb);
  }
  __builtin_amdgcn_s_setprio(1);
#pragma unroll
  for (int i = 0; i < 8; ++i)
#pragma unroll
    for (int j = 0; j < 3; ++j) {
      int aj = (j < 2) ? j : (HN ? 3 : 2);
      acc[i][aj] = __builtin_amdgcn_mfma_f32_16x16x32_bf16(af[i], bfr[j], acc[i][aj], 0, 0, 0);
    }
  __builtin_amdgcn_s_setprio(0);
}

// ---------------- GEMM: C = A @ Bw^T (+bias), 256x256 tile (EPI0/EPI1) ---------
// R10 core — best measured for these shapes. 2 barriers/tile, vmcnt(8) counted.
// GA: A0 rows gathered through par[] (gload_lds global src is per-lane).
// NOTE: never request >2 waves/SIMD — acc alone is 128 regs (R2: spill, 3x).
template <int EPI, int KTOT, int KSPLIT, bool GA>
__global__ __launch_bounds__(512, 2)
void k_gemm(const us* __restrict__ A0, const us* __restrict__ A1, int strideA,
            const us* __restrict__ Bw, const float* __restrict__ bias,
            us* __restrict__ outBf, float* __restrict__ outF, int writeF32,
            const int* __restrict__ par) {
  __shared__ __align__(16) us As[2][256 * 64];
  __shared__ __align__(16) us Bs[2][256 * 64];
  int tid = threadIdx.x;
  int w = tid >> 6, l = tid & 63;
  int wr = w >> 2, wc = w & 3;
  int bid = blockIdx.x;
  int per = gridDim.x >> 3;
  int mi = (bid & 7) * per + (bid >> 3);   // XCD-chunked, single n-tile
  int mBase = mi * 256;
  f32x4 acc[8][4] = {};

  int prow[4];
  if (GA) {
    int bb = (mBase >> 12) << 12;
#pragma unroll
    for (int c = 0; c < 4; ++c)
      prow[c] = bb + par[mBase + c * 64 + (tid >> 3)];
  }

  auto stage = [&](int t) {
    int kt = t * 64, buf = t & 1;
    const us* aSrc; int kOff;
    if (kt < KSPLIT) { aSrc = A0; kOff = kt; }
    else             { aSrc = A1; kOff = kt - KSPLIT; }
#pragma unroll
    for (int c = 0; c < 4; ++c) {
      int row = c * 64 + (tid >> 3);
      int kb = ((tid & 7) * 16) ^ ((row & 7) << 4);   // pre-swizzled global source
      const char* ga;
      if (GA && kt < KSPLIT)
        ga = (const char*)(aSrc + (size_t)prow[c] * strideA + kOff) + kb;
      else
        ga = (const char*)(aSrc + (size_t)(mBase + row) * strideA + kOff) + kb;
      gload_lds16(ga, (char*)As[buf] + row * 128 + (tid & 7) * 16);
      const char* gb = (const char*)(Bw + (size_t)row * KTOT + kt) + kb;
      gload_lds16(gb, (char*)Bs[buf] + row * 128 + (tid & 7) * 16);
    }
  };

  constexpr int NKT = KTOT / 64;
  stage(0);
#pragma unroll
  for (int t = 0; t < NKT; ++t) {
    if (t + 1 < NKT) {
      stage(t + 1);
      asm volatile("s_waitcnt vmcnt(8)" ::: "memory");  // tile t done; t+1 in flight
    } else {
      asm volatile("s_waitcnt vmcnt(0)" ::: "memory");
    }
    raw_barrier();
    mma8(As[t & 1], Bs[t & 1], wr, wc, l, acc);
    raw_barrier();
  }

  int rBase0 = mBase + wr * 128;
  int cBase0 = wc * 64;
#pragma unroll
  for (int i = 0; i < 8; ++i)
#pragma unroll
    for (int j = 0; j < 4; ++j) {
      int col = cBase0 + j * 16 + (l & 15);
      int row0 = rBase0 + i * 16 + ((l >> 4) << 2);
      float bb = bias[col];
#pragma unroll
      for (int e = 0; e < 4; ++e) {
        float v = acc[i][j][e] + bb;
        size_t off = (size_t)(row0 + e) * 256 + col;
        outBf[off] = f2bf(v);
        if (EPI == 1 && writeF32) outF[off] = v;
      }
    }
}

// ---------------- gates GEMM: [h|s] @ packed-Wg, T3/T4/T5 pipeline -------------
// R17: depth-2 counted pipeline + ks-phase split + setprio, 2 barriers/tile.
// As triple-buffered (depth-2 A prefetch, 96 KB), Bs double-buffered (48 KB).
// Per tile t: issue stageA(t+2) [4] + stageB(t+1) [3] -> vmcnt(11) (A(t),B(t)
// landed; 11 future loads STAY IN FLIGHT — never drains mid-loop; tail 7/0)
// -> barrier -> phase ks=0 {11 ds_read, setprio, 24 MFMA} -> phase ks=1 ->
// barrier. Phases need no barrier between them (intra-tile reads are read-only
// on resident buffers). Rotation safety: A buf (t+2)%3 / B buf (t+1)&1 were
// last read by tile t-1, whose end barrier precedes the issue point.
// sv: it<2 -> bf16 sbf; final it -> exact f32 sF.
__global__ __launch_bounds__(512, 2)
void k_gates(const us* __restrict__ h, const us* __restrict__ s,
             const us* __restrict__ Wgh, const us* __restrict__ Wgs,
             const float* __restrict__ bg,
             us* __restrict__ outBf, float* __restrict__ outF,
             const us* __restrict__ svBf, const float* __restrict__ sF,
             int finalIt) {
  __shared__ __align__(16) us As[3][256 * 64];   // 96 KB (triple buffer)
  __shared__ __align__(16) us Bs[2][192 * 64];   // 48 KB (double buffer)
  int tid = threadIdx.x;
  int w = tid >> 6, l = tid & 63;
  int wr = w >> 2, wc = w & 3;
  int bid = blockIdx.x;
  int per = gridDim.x >> 3;
  int g = (bid & 7) * per + (bid >> 3);
  int mi = g >> 2, ni = g & 3;                   // NT=4
  int mBase = mi * 256, nB = ni * 192, nBase = ni * 256;
  f32x4 acc[8][4] = {};

  auto stageA = [&](int t) {                     // 4 loads -> As[t % 3]
    int buf = t % 3;
    const us* aSrc = (t < 4) ? h : s;
    int kOff = (t & 3) * 64;
#pragma unroll
    for (int c = 0; c < 4; ++c) {
      int row = c * 64 + (tid >> 3);
      int kb = ((tid & 7) * 16) ^ ((row & 7) << 4);
      gload_lds16((const char*)(aSrc + (size_t)(mBase + row) * 256 + kOff) + kb,
                  (char*)As[buf] + row * 128 + (tid & 7) * 16);
    }
  };
  auto stageB = [&](int t) {                     // 3 loads -> Bs[t & 1]
    int buf = t & 1;
    const us* bSrc = (t < 4) ? Wgh : Wgs;
    int kOff = (t & 3) * 64;
#pragma unroll
    for (int c = 0; c < 3; ++c) {
      int row = c * 64 + (tid >> 3);
      int kb = ((tid & 7) * 16) ^ ((row & 7) << 4);
      gload_lds16((const char*)(bSrc + (size_t)(nB + row) * 256 + kOff) + kb,
                  (char*)Bs[buf] + row * 128 + (tid & 7) * 16);
    }
  };

  // prologue: A depth-2, B depth-1
  stageA(0); stageB(0); stageA(1);
#pragma unroll
  for (int t = 0; t < 8; ++t) {
    if (t + 2 < 8) stageA(t + 2);
    if (t + 1 < 8) stageB(t + 1);
    // counted waits: outstanding after wait = A-beyond-t * 4 + B-beyond-t * 3
    if (t <= 5)      asm volatile("s_waitcnt vmcnt(11)" ::: "memory");
    else if (t == 6) asm volatile("s_waitcnt vmcnt(7)" ::: "memory");
    else             asm volatile("s_waitcnt vmcnt(0)" ::: "memory");
    raw_barrier();                   // As[t%3] / Bs[t&1] visible to all waves
    const us* A = As[t % 3];
    const us* B = Bs[t & 1];
    if (t < 4) {
      mma8g_ks<0, 0>(A, B, wr, wc, l, acc);   // phase ks=0, slot2 -> xn
      mma8g_ks<0, 1>(A, B, wr, wc, l, acc);   // phase ks=1
    } else {
      mma8g_ks<1, 0>(A, B, wr, wc, l, acc);   // slot2 -> hn
      mma8g_ks<1, 1>(A, B, wr, wc, l, acc);
    }
    raw_barrier();                   // all reads done before buffers re-staged
  }

  // shuffle-free GRU epilogue: acc j == gate {r, z, xn, hn}
  int rBase0 = mBase + wr * 128;
  int cB = nBase + wc * 64;
  int outCol = ((nBase >> 6) + wc) * 16 + (l & 15);
  float b0 = bg[cB + 0  + (l & 15)];
  float b1 = bg[cB + 16 + (l & 15)];
  float b2 = bg[cB + 32 + (l & 15)];
  float b3 = bg[cB + 48 + (l & 15)];
#pragma unroll
  for (int i = 0; i < 8; ++i) {
    int row0 = rBase0 + i * 16 + ((l >> 4) << 2);
#pragma unroll
    for (int e = 0; e < 4; ++e) {
      float r = sigf(acc[i][0][e] + b0);
      float z = sigf(acc[i][1][e] + b1);
      float n = tanhfast(acc[i][2][e] + b2 + r * (acc[i][3][e] + b3));
      size_t off = (size_t)(row0 + e) * 256 + outCol;
      float sv = finalIt ? sF[off] : bf2f(svBf[off]);
      float o = (1.f - z) * n + z * sv;
      if (finalIt) outF[off] = o;
      else         outBf[off] = f2bf(o);
    }
  }
}

extern "C" void kernel_launch(void* const* d_in, const int* in_sizes, int n_in,
                              void* d_out, int out_size, void* d_ws, size_t ws_size,
                              hipStream_t stream) {
  const float* x    = (const float*)d_in[0];
  const int*   par  = (const int*)d_in[1];
  const int*   chd  = (const int*)d_in[2];
  const int*   cnt  = (const int*)d_in[3];
  const float* Wres = (const float*)d_in[4];
  const float* bres = (const float*)d_in[5];
  const float* Wpar = (const float*)d_in[6];
  const float* bpar = (const float*)d_in[7];
  const float* Wnbr = (const float*)d_in[8];
  const float* bnbr = (const float*)d_in[9];
  const float* Wih  = (const float*)d_in[10];
  const float* Whh  = (const float*)d_in[11];
  const float* bih  = (const float*)d_in[12];
  const float* bhh  = (const float*)d_in[13];

  char* ws = (char*)d_ws;
  size_t off = 0;
  auto alloc = [&](size_t sz) { char* p = ws + off; off += (sz + 255) & ~(size_t)255; return p; };
  us*    Wgh  = (us*)alloc((size_t)768 * 256 * 2);
  us*    Wgs  = (us*)alloc((size_t)768 * 256 * 2);
  us*    Wcat = (us*)alloc((size_t)256 * 512 * 2);
  us*    Wr   = (us*)alloc((size_t)256 * 256 * 2);
  float* bcat = (float*)alloc(256 * 4);
  float* bg   = (float*)alloc(1024 * 4);
  us*    xbf  = (us*)alloc((size_t)MM * 256 * 2);  // reused as s_bf after resize
  us*    h0   = (us*)alloc((size_t)MM * 256 * 2);
  us*    h1   = (us*)alloc((size_t)MM * 256 * 2);
  us*    nbr  = (us*)alloc((size_t)MM * 256 * 2);
  us*    sbf  = xbf;
  float* sF   = (float*)d_out;  // f32 s scratch in d_out (final iter only;
                                // each slot overwritten after its own sv read)

  k_prep<<<256, 256, 0, stream>>>(Wres, Wpar, bpar, Wnbr, bnbr, Wih, Whh, bih, bhh,
                                  Wr, Wcat, bcat, Wgh, Wgs, bg);
  k_f2bf<<<(MM * 256 / 8) / 256, 256, 0, stream>>>(x, xbf, MM * 256 / 8);

  // h0 = x @ W_resize^T + b_resize   (M/256 = 256 blocks, single n-tile)
  k_gemm<0, 256, 256, false><<<256, 512, 0, stream>>>(
      xbf, xbf, 256, Wr, bres, h0, nullptr, 0, nullptr);

  us* hc = h0;
  for (int it = 0; it < 3; ++it) {
    us* hn = (hc == h0) ? h1 : h0;
    k_child<<<MM / 4, 256, 0, stream>>>(hc, chd, cnt, nbr);
    // s = [h[par] | nbr] @ Wcat^T + bcat  (parent gather fused into staging;
    // f32 sF written only on the final iteration)
    k_gemm<1, 512, 256, true><<<256, 512, 0, stream>>>(
        hc, nbr, 256, Wcat, bcat, sbf, sF, (it == 2) ? 1 : 0, par);
    // gates = [h|s] @ packed-Wg, fused GRU -> h_next (bf16) or d_out (f32)
    k_gates<<<1024, 512, 0, stream>>>(
        hc, sbf, Wgh, Wgs, bg, hn, (float*)d_out, sbf, sF, (it == 2) ? 1 : 0);
    hc = hn;
  }
}

// Round 18
// 427.561 us; speedup vs baseline: 1.8509x; 1.1318x over previous
//
#include <hip/hip_runtime.h>

typedef unsigned short us;
typedef us us4 __attribute__((ext_vector_type(4)));
typedef us us8 __attribute__((ext_vector_type(8)));
typedef short bf16x8 __attribute__((ext_vector_type(8)));
typedef float f32x4 __attribute__((ext_vector_type(4)));

#define DEVI static __device__ __forceinline__

// constants for this problem instance
#define BB 16
#define NN 4096
#define PP 256
#define CC 8
#define MM (BB * NN)   // 65536

DEVI float bf2f(us u) { unsigned x = ((unsigned)u) << 16; return __builtin_bit_cast(float, x); }
DEVI us f2bf(float f) {
  unsigned x = __builtin_bit_cast(unsigned, f);
  x += 0x7fffu + ((x >> 16) & 1u);   // round to nearest even
  return (us)(x >> 16);
}

DEVI void gload_lds16(const void* g, void* l) {
  __builtin_amdgcn_global_load_lds(
      (const __attribute__((address_space(1))) void*)g,
      (__attribute__((address_space(3))) void*)l, 16, 0, 0);
}

DEVI float sigf(float x) { return 1.f / (1.f + __expf(-x)); }
DEVI float tanhfast(float a) {
  float aa = fabsf(a);
  float t = 1.f - 2.f / (1.f + __expf(2.f * aa));
  return copysignf(t, a);
}

DEVI void raw_barrier() {
  __builtin_amdgcn_sched_barrier(0);
  __builtin_amdgcn_s_barrier();      // RAW barrier: no implicit vmcnt(0) drain
  __builtin_amdgcn_sched_barrier(0);
}

// ---------------- weight prep ---------------------------------------------------
// Wcat[256][512] = [W_parent | W_nbr]; bcat = bpar + bnbr.
// Packed gates weights (192-row B-tiles, no dead rows):
//   Wgh[768][256] (h-half, from Wih) / Wgs[768][256] (s-half, from Whh):
//   row R -> J16 = R/48, slot = (R/16)%3; j_out = J16*16 + (R&15);
//   slot 0 = r, slot 1 = z, slot 2 = n (xn / hn).
__global__ void k_prep(const float* __restrict__ Wres,
                       const float* __restrict__ Wpar, const float* __restrict__ bpar,
                       const float* __restrict__ Wnbr, const float* __restrict__ bnbr,
                       const float* __restrict__ Wih, const float* __restrict__ Whh,
                       const float* __restrict__ bih, const float* __restrict__ bhh,
                       us* __restrict__ Wr, us* __restrict__ Wcat, float* __restrict__ bcat,
                       us* __restrict__ Wgh, us* __restrict__ Wgs, float* __restrict__ bg) {
  int tid = blockIdx.x * blockDim.x + threadIdx.x;
  int nth = gridDim.x * blockDim.x;
  for (int i = tid; i < 256 * 256; i += nth) Wr[i] = f2bf(Wres[i]);
  for (int i = tid; i < 256 * 512; i += nth) {
    int o = i >> 9, k = i & 511;
    float v = (k < 256) ? Wpar[o * 256 + k] : Wnbr[o * 256 + (k - 256)];
    Wcat[i] = f2bf(v);
  }
  for (int i = tid; i < 256; i += nth) bcat[i] = bpar[i] + bnbr[i];
  for (int i = tid; i < 768 * 256; i += nth) {
    int R = i >> 8, k = i & 255;
    int j = (R / 48) * 16 + (R & 15);
    int slot = (R >> 4) % 3;                     // 0=r 1=z 2=n
    Wgh[i] = f2bf(Wih[(size_t)(slot * 256 + j) * 256 + k]);
    Wgs[i] = f2bf(Whh[(size_t)(slot * 256 + j) * 256 + k]);
  }
  for (int i = tid; i < 1024; i += nth) {
    int g = (i >> 4) & 3, j = ((i >> 6) << 4) + (i & 15);
    float v;
    if (g == 0)      v = bih[j] + bhh[j];
    else if (g == 1) v = bih[256 + j] + bhh[256 + j];
    else if (g == 2) v = bih[512 + j];
    else             v = bhh[512 + j];
    bg[i] = v;
  }
}

// ---------------- MFMA K-step (256x256 tile), full 4-j --------------------------
DEVI void mma8(const us* As, const us* Bs, int wr, int wc, int l,
               f32x4 (&acc)[8][4]) {
#pragma unroll
  for (int ks = 0; ks < 2; ++ks) {
    bf16x8 af[8], bfr[4];
#pragma unroll
    for (int i = 0; i < 8; ++i) {
      int row = wr * 128 + i * 16 + (l & 15);
      int kb = ((ks * 32 + (l >> 4) * 8) * 2) ^ ((row & 7) << 4);  // swizzled read
      af[i] = *(const bf16x8*)((const char*)As + row * 128 + kb);
    }
#pragma unroll
    for (int j = 0; j < 4; ++j) {
      int row = wc * 64 + j * 16 + (l & 15);
      int kb = ((ks * 32 + (l >> 4) * 8) * 2) ^ ((row & 7) << 4);
      bfr[j] = *(const bf16x8*)((const char*)Bs + row * 128 + kb);
    }
#pragma unroll
    for (int i = 0; i < 8; ++i)
#pragma unroll
      for (int j = 0; j < 4; ++j)
        acc[i][j] = __builtin_amdgcn_mfma_f32_16x16x32_bf16(af[i], bfr[j], acc[i][j], 0, 0, 0);
  }
}

// ---------------- MFMA phase (gates): one ks-subset, 192-row packed B ----------
template <int HN, int KS>
DEVI void mma8g_ks(const us* As, const us* Bs, int wr, int wc, int l,
                   f32x4 (&acc)[8][4]) {
  bf16x8 af[8], bfr[3];
#pragma unroll
  for (int i = 0; i < 8; ++i) {
    int row = wr * 128 + i * 16 + (l & 15);
    int kb = ((KS * 32 + (l >> 4) * 8) * 2) ^ ((row & 7) << 4);
    af[i] = *(const bf16x8*)((const char*)As + row * 128 + kb);
  }
#pragma unroll
  for (int j = 0; j < 3; ++j) {
    int row = wc * 48 + j * 16 + (l & 15);
    int kb = ((KS * 32 + (l >> 4) * 8) * 2) ^ ((row & 7) << 4);
    bfr[j] = *(const bf16x8*)((const char*)Bs + row * 128 + kb);
  }
  __builtin_amdgcn_s_setprio(1);
#pragma unroll
  for (int i = 0; i < 8; ++i)
#pragma unroll
    for (int j = 0; j < 3; ++j) {
      int aj = (j < 2) ? j : (HN ? 3 : 2);
      acc[i][aj] = __builtin_amdgcn_mfma_f32_16x16x32_bf16(af[i], bfr[j], acc[i][aj], 0, 0, 0);
    }
  __builtin_amdgcn_s_setprio(0);
}

// ---------------- resize GEMM: h0 = x(f32) @ Wr^T + bres -----------------------
// R18: reads x f32 DIRECTLY (k_f2bf dispatch eliminated). A staged via
// reg-convert: load 8 f32 from the SWIZZLED source offset, f2bf, ds_write_b128
// to the LINEAR slot (same both-sides-swizzle identity as gload staging).
// Simple drain sync (only 4 k-tiles; prefetch value low).
__global__ __launch_bounds__(512, 2)
void k_gemm0(const float* __restrict__ x, const us* __restrict__ Bw,
             const float* __restrict__ bias, us* __restrict__ outBf) {
  __shared__ __align__(16) us As[256 * 64];
  __shared__ __align__(16) us Bs[256 * 64];
  int tid = threadIdx.x;
  int w = tid >> 6, l = tid & 63;
  int wr = w >> 2, wc = w & 3;
  int bid = blockIdx.x;
  int per = gridDim.x >> 3;
  int mi = (bid & 7) * per + (bid >> 3);
  int mBase = mi * 256;
  f32x4 acc[8][4] = {};

#pragma unroll
  for (int t = 0; t < 4; ++t) {
    int kt = t * 64;
#pragma unroll
    for (int c = 0; c < 4; ++c) {
      int row = c * 64 + (tid >> 3);
      int kbb = ((tid & 7) * 16) ^ ((row & 7) << 4);   // bf16-byte offset (swizzled src)
      const float* src = x + (size_t)(mBase + row) * 256 + kt + (kbb >> 1);
      float4 a = *(const float4*)src;
      float4 b = *(const float4*)(src + 4);
      us8 v;
      v[0] = f2bf(a.x); v[1] = f2bf(a.y); v[2] = f2bf(a.z); v[3] = f2bf(a.w);
      v[4] = f2bf(b.x); v[5] = f2bf(b.y); v[6] = f2bf(b.z); v[7] = f2bf(b.w);
      *(us8*)((char*)As + row * 128 + (tid & 7) * 16) = v;  // linear dest
      int kb = ((tid & 7) * 16) ^ ((row & 7) << 4);
      gload_lds16((const char*)(Bw + (size_t)row * 256 + kt) + kb,
                  (char*)Bs + row * 128 + (tid & 7) * 16);
    }
    asm volatile("s_waitcnt vmcnt(0)" ::: "memory");
    __syncthreads();                  // drains lgkm (ds_writes) + barrier
    mma8(As, Bs, wr, wc, l, acc);
    __syncthreads();
  }

  int rBase0 = mBase + wr * 128;
  int cBase0 = wc * 64;
#pragma unroll
  for (int i = 0; i < 8; ++i)
#pragma unroll
    for (int j = 0; j < 4; ++j) {
      int col = cBase0 + j * 16 + (l & 15);
      int row0 = rBase0 + i * 16 + ((l >> 4) << 2);
      float bb = bias[col];
#pragma unroll
      for (int e = 0; e < 4; ++e)
        outBf[(size_t)(row0 + e) * 256 + col] = f2bf(acc[i][j][e] + bb);
    }
}

// ---------------- s GEMM: s = [h[par] | avg(h[children])] @ Wcat^T + bcat ------
// R18: k_child ELIMINATED — children-average computed inline during A1 staging
// (tiles 4-7): reg-gather 8 child slices (two rounds of 4 to cap live VGPR),
// mask-average f32, f2bf, ds_write_b128 to linear slot of the swizzled source
// offset (bit-identical to the old k_child+gload path). Eager child-load waits
// FIFO-drain A(t)/B(t) automatically; after lgkmcnt(0) only B(t+1)'s 4 gloads
// remain in flight -> vmcnt(4). Tiles 0-3 keep the GA gload path (vmcnt(8)).
__global__ __launch_bounds__(512, 2)
void k_sgemm(const us* __restrict__ h, const int* __restrict__ par,
             const int* __restrict__ chd, const int* __restrict__ cnt,
             const us* __restrict__ Wcat, const float* __restrict__ bcat,
             us* __restrict__ outBf, float* __restrict__ outF, int writeF32) {
  __shared__ __align__(16) us As[2][256 * 64];
  __shared__ __align__(16) us Bs[2][256 * 64];
  int tid = threadIdx.x;
  int w = tid >> 6, l = tid & 63;
  int wr = w >> 2, wc = w & 3;
  int bid = blockIdx.x;
  int per = gridDim.x >> 3;
  int mi = (bid & 7) * per + (bid >> 3);
  int mBase = mi * 256;
  int bb = (mBase >> 12) << 12;       // batch base row
  f32x4 acc[8][4] = {};

  int prow[4];
#pragma unroll
  for (int c = 0; c < 4; ++c)
    prow[c] = bb + par[mBase + c * 64 + (tid >> 3)];

  auto stageB = [&](int t) {
    int kt = t * 64, buf = t & 1;
#pragma unroll
    for (int c = 0; c < 4; ++c) {
      int row = c * 64 + (tid >> 3);
      int kb = ((tid & 7) * 16) ^ ((row & 7) << 4);
      gload_lds16((const char*)(Wcat + (size_t)row * 512 + kt) + kb,
                  (char*)Bs[buf] + row * 128 + (tid & 7) * 16);
    }
  };
  auto stageG = [&](int t) {          // tiles 0..3: h[parent] via gload (GA)
    int kt = t * 64, buf = t & 1;
#pragma unroll
    for (int c = 0; c < 4; ++c) {
      int row = c * 64 + (tid >> 3);
      int kb = ((tid & 7) * 16) ^ ((row & 7) << 4);
      gload_lds16((const char*)(h + (size_t)prow[c] * 256 + kt) + kb,
                  (char*)As[buf] + row * 128 + (tid & 7) * 16);
    }
    stageB(t);
  };
  auto stageN = [&](int t) {          // tiles 4..7: inline children-average
    int kt = t * 64, buf = t & 1;
    int kOffBase = kt - 256;
#pragma unroll
    for (int c = 0; c < 4; ++c) {
      int row = c * 64 + (tid >> 3);
      int m = mBase + row;
      int kbb = ((tid & 7) * 16) ^ ((row & 7) << 4);
      const us* hb = h + (size_t)bb * 256 + kOffBase + (kbb >> 1);
      int4 c0 = *(const int4*)(chd + (size_t)m * CC);
      int4 c1 = *(const int4*)(chd + (size_t)m * CC + 4);
      int ci[8] = {c0.x, c0.y, c0.z, c0.w, c1.x, c1.y, c1.z, c1.w};
      int cn = cnt[m];
      float aa[8] = {0.f, 0.f, 0.f, 0.f, 0.f, 0.f, 0.f, 0.f};
#pragma unroll
      for (int r2 = 0; r2 < 2; ++r2) {           // two rounds of 4 children
        us8 cv[4];
#pragma unroll
        for (int i2 = 0; i2 < 4; ++i2)
          cv[i2] = *(const us8*)(hb + (size_t)ci[r2 * 4 + i2] * 256);
#pragma unroll
        for (int i2 = 0; i2 < 4; ++i2) {
          float wgt = (r2 * 4 + i2 < cn) ? 1.f : 0.f;
#pragma unroll
          for (int e = 0; e < 8; ++e) aa[e] += wgt * bf2f(cv[i2][e]);
        }
      }
      float inv = 1.f / (float)cn;
      us8 nb;
#pragma unroll
      for (int e = 0; e < 8; ++e) nb[e] = f2bf(aa[e] * inv);
      *(us8*)((char*)As[buf] + row * 128 + (tid & 7) * 16) = nb;
    }
    asm volatile("s_waitcnt lgkmcnt(0)" ::: "memory");  // ds_writes done pre-barrier
    stageB(t);
  };

  stageG(0);
#pragma unroll
  for (int t = 0; t < 8; ++t) {
    if (t + 1 < 8) {
      if (t + 1 < 4) stageG(t + 1);
      else           stageN(t + 1);
    }
    if (t + 1 < 4)      asm volatile("s_waitcnt vmcnt(8)" ::: "memory");
    else if (t < 7)     asm volatile("s_waitcnt vmcnt(4)" ::: "memory");
    else                asm volatile("s_waitcnt vmcnt(0)" ::: "memory");
    raw_barrier();
    mma8(As[t & 1], Bs[t & 1], wr, wc, l, acc);
    raw_barrier();
  }

  int rBase0 = mBase + wr * 128;
  int cBase0 = wc * 64;
#pragma unroll
  for (int i = 0; i < 8; ++i)
#pragma unroll
    for (int j = 0; j < 4; ++j) {
      int col = cBase0 + j * 16 + (l & 15);
      int row0 = rBase0 + i * 16 + ((l >> 4) << 2);
      float bbia = bcat[col];
#pragma unroll
      for (int e = 0; e < 4; ++e) {
        float v = acc[i][j][e] + bbia;
        size_t off = (size_t)(row0 + e) * 256 + col;
        outBf[off] = f2bf(v);
        if (writeF32) outF[off] = v;
      }
    }
}

// ---------------- gates GEMM: [h|s] @ packed-Wg, fused GRU (R17 form) ----------
__global__ __launch_bounds__(512, 2)
void k_gates(const us* __restrict__ h, const us* __restrict__ s,
             const us* __restrict__ Wgh, const us* __restrict__ Wgs,
             const float* __restrict__ bg,
             us* __restrict__ outBf, float* __restrict__ outF,
             const us* __restrict__ svBf, const float* __restrict__ sF,
             int finalIt) {
  __shared__ __align__(16) us As[3][256 * 64];   // 96 KB (triple buffer, depth-2)
  __shared__ __align__(16) us Bs[2][192 * 64];   // 48 KB
  int tid = threadIdx.x;
  int w = tid >> 6, l = tid & 63;
  int wr = w >> 2, wc = w & 3;
  int bid = blockIdx.x;
  int per = gridDim.x >> 3;
  int g = (bid & 7) * per + (bid >> 3);
  int mi = g >> 2, ni = g & 3;                   // NT=4
  int mBase = mi * 256, nB = ni * 192, nBase = ni * 256;
  f32x4 acc[8][4] = {};

  auto stageA = [&](int t) {
    int buf = t % 3;
    const us* aSrc = (t < 4) ? h : s;
    int kOff = (t & 3) * 64;
#pragma unroll
    for (int c = 0; c < 4; ++c) {
      int row = c * 64 + (tid >> 3);
      int kb = ((tid & 7) * 16) ^ ((row & 7) << 4);
      gload_lds16((const char*)(aSrc + (size_t)(mBase + row) * 256 + kOff) + kb,
                  (char*)As[buf] + row * 128 + (tid & 7) * 16);
    }
  };
  auto stageBw = [&](int t) {
    int buf = t & 1;
    const us* bSrc = (t < 4) ? Wgh : Wgs;
    int kOff = (t & 3) * 64;
#pragma unroll
    for (int c = 0; c < 3; ++c) {
      int row = c * 64 + (tid >> 3);
      int kb = ((tid & 7) * 16) ^ ((row & 7) << 4);
      gload_lds16((const char*)(bSrc + (size_t)(nB + row) * 256 + kOff) + kb,
                  (char*)Bs[buf] + row * 128 + (tid & 7) * 16);
    }
  };

  stageA(0); stageBw(0); stageA(1);
#pragma unroll
  for (int t = 0; t < 8; ++t) {
    if (t + 2 < 8) stageA(t + 2);
    if (t + 1 < 8) stageBw(t + 1);
    if (t <= 5)      asm volatile("s_waitcnt vmcnt(11)" ::: "memory");
    else if (t == 6) asm volatile("s_waitcnt vmcnt(7)" ::: "memory");
    else             asm volatile("s_waitcnt vmcnt(0)" ::: "memory");
    raw_barrier();
    const us* A = As[t % 3];
    const us* B = Bs[t & 1];
    if (t < 4) {
      mma8g_ks<0, 0>(A, B, wr, wc, l, acc);
      mma8g_ks<0, 1>(A, B, wr, wc, l, acc);
    } else {
      mma8g_ks<1, 0>(A, B, wr, wc, l, acc);
      mma8g_ks<1, 1>(A, B, wr, wc, l, acc);
    }
    raw_barrier();
  }

  int rBase0 = mBase + wr * 128;
  int cB = nBase + wc * 64;
  int outCol = ((nBase >> 6) + wc) * 16 + (l & 15);
  float b0 = bg[cB + 0  + (l & 15)];
  float b1 = bg[cB + 16 + (l & 15)];
  float b2 = bg[cB + 32 + (l & 15)];
  float b3 = bg[cB + 48 + (l & 15)];
#pragma unroll
  for (int i = 0; i < 8; ++i) {
    int row0 = rBase0 + i * 16 + ((l >> 4) << 2);
#pragma unroll
    for (int e = 0; e < 4; ++e) {
      float r = sigf(acc[i][0][e] + b0);
      float z = sigf(acc[i][1][e] + b1);
      float n = tanhfast(acc[i][2][e] + b2 + r * (acc[i][3][e] + b3));
      size_t off = (size_t)(row0 + e) * 256 + outCol;
      float sv = finalIt ? sF[off] : bf2f(svBf[off]);
      float o = (1.f - z) * n + z * sv;
      if (finalIt) outF[off] = o;
      else         outBf[off] = f2bf(o);
    }
  }
}

extern "C" void kernel_launch(void* const* d_in, const int* in_sizes, int n_in,
                              void* d_out, int out_size, void* d_ws, size_t ws_size,
                              hipStream_t stream) {
  const float* x    = (const float*)d_in[0];
  const int*   par  = (const int*)d_in[1];
  const int*   chd  = (const int*)d_in[2];
  const int*   cnt  = (const int*)d_in[3];
  const float* Wres = (const float*)d_in[4];
  const float* bres = (const float*)d_in[5];
  const float* Wpar = (const float*)d_in[6];
  const float* bpar = (const float*)d_in[7];
  const float* Wnbr = (const float*)d_in[8];
  const float* bnbr = (const float*)d_in[9];
  const float* Wih  = (const float*)d_in[10];
  const float* Whh  = (const float*)d_in[11];
  const float* bih  = (const float*)d_in[12];
  const float* bhh  = (const float*)d_in[13];

  char* ws = (char*)d_ws;
  size_t off = 0;
  auto alloc = [&](size_t sz) { char* p = ws + off; off += (sz + 255) & ~(size_t)255; return p; };
  us*    Wgh  = (us*)alloc((size_t)768 * 256 * 2);
  us*    Wgs  = (us*)alloc((size_t)768 * 256 * 2);
  us*    Wcat = (us*)alloc((size_t)256 * 512 * 2);
  us*    Wr   = (us*)alloc((size_t)256 * 256 * 2);
  float* bcat = (float*)alloc(256 * 4);
  float* bg   = (float*)alloc(1024 * 4);
  us*    sbf  = (us*)alloc((size_t)MM * 256 * 2);
  us*    h0   = (us*)alloc((size_t)MM * 256 * 2);
  us*    h1   = (us*)alloc((size_t)MM * 256 * 2);
  float* sF   = (float*)d_out;  // f32 s scratch in d_out (final iter only;
                                // each slot overwritten after its own sv read)

  k_prep<<<256, 256, 0, stream>>>(Wres, Wpar, bpar, Wnbr, bnbr, Wih, Whh, bih, bhh,
                                  Wr, Wcat, bcat, Wgh, Wgs, bg);

  // h0 = x(f32) @ W_resize^T + b_resize   (direct f32 read; f2bf eliminated)
  k_gemm0<<<256, 512, 0, stream>>>(x, Wr, bres, h0);

  us* hc = h0;
  for (int it = 0; it < 3; ++it) {
    us* hn = (hc == h0) ? h1 : h0;
    // s = [h[par] | avg(h[children])] @ Wcat^T + bcat  (k_child eliminated —
    // children-average inlined into staging; f32 sF written final iter only)
    k_sgemm<<<256, 512, 0, stream>>>(hc, par, chd, cnt, Wcat, bcat,
                                     sbf, sF, (it == 2) ? 1 : 0);
    // gates = [h|s] @ packed-Wg, fused GRU -> h_next (bf16) or d_out (f32)
    k_gates<<<1024, 512, 0, stream>>>(
        hc, sbf, Wgh, Wgs, bg, hn, (float*)d_out, sbf, sF, (it == 2) ? 1 : 0);
    hc = hn;
  }
}

// Round 19
// 414.311 us; speedup vs baseline: 1.9101x; 1.0320x over previous
//
#include <hip/hip_runtime.h>

typedef unsigned short us;
typedef us us4 __attribute__((ext_vector_type(4)));
typedef us us8 __attribute__((ext_vector_type(8)));
typedef short bf16x8 __attribute__((ext_vector_type(8)));
typedef float f32x4 __attribute__((ext_vector_type(4)));

#define DEVI static __device__ __forceinline__

// constants for this problem instance
#define BB 16
#define NN 4096
#define PP 256
#define CC 8
#define MM (BB * NN)   // 65536

DEVI float bf2f(us u) { unsigned x = ((unsigned)u) << 16; return __builtin_bit_cast(float, x); }
DEVI us f2bf(float f) {
  unsigned x = __builtin_bit_cast(unsigned, f);
  x += 0x7fffu + ((x >> 16) & 1u);   // round to nearest even
  return (us)(x >> 16);
}

DEVI void gload_lds16(const void* g, void* l) {
  __builtin_amdgcn_global_load_lds(
      (const __attribute__((address_space(1))) void*)g,
      (__attribute__((address_space(3))) void*)l, 16, 0, 0);
}

DEVI float sigf(float x) { return 1.f / (1.f + __expf(-x)); }
DEVI float tanhfast(float a) {
  float aa = fabsf(a);
  float t = 1.f - 2.f / (1.f + __expf(2.f * aa));
  return copysignf(t, a);
}

DEVI void raw_barrier() {
  __builtin_amdgcn_sched_barrier(0);
  __builtin_amdgcn_s_barrier();      // RAW barrier: no implicit vmcnt(0) drain
  __builtin_amdgcn_sched_barrier(0);
}

// ---------------- weight prep ---------------------------------------------------
// Wcat[256][512] = [W_parent | W_nbr]; bcat = bpar + bnbr.
// Packed gates weights (192-row B-tiles, no dead rows):
//   Wgh[768][256] (h-half, from Wih) / Wgs[768][256] (s-half, from Whh):
//   row R -> J16 = R/48, slot = (R/16)%3; j_out = J16*16 + (R&15);
//   slot 0 = r, slot 1 = z, slot 2 = n (xn / hn).
__global__ void k_prep(const float* __restrict__ Wres,
                       const float* __restrict__ Wpar, const float* __restrict__ bpar,
                       const float* __restrict__ Wnbr, const float* __restrict__ bnbr,
                       const float* __restrict__ Wih, const float* __restrict__ Whh,
                       const float* __restrict__ bih, const float* __restrict__ bhh,
                       us* __restrict__ Wr, us* __restrict__ Wcat, float* __restrict__ bcat,
                       us* __restrict__ Wgh, us* __restrict__ Wgs, float* __restrict__ bg) {
  int tid = blockIdx.x * blockDim.x + threadIdx.x;
  int nth = gridDim.x * blockDim.x;
  for (int i = tid; i < 256 * 256; i += nth) Wr[i] = f2bf(Wres[i]);
  for (int i = tid; i < 256 * 512; i += nth) {
    int o = i >> 9, k = i & 511;
    float v = (k < 256) ? Wpar[o * 256 + k] : Wnbr[o * 256 + (k - 256)];
    Wcat[i] = f2bf(v);
  }
  for (int i = tid; i < 256; i += nth) bcat[i] = bpar[i] + bnbr[i];
  for (int i = tid; i < 768 * 256; i += nth) {
    int R = i >> 8, k = i & 255;
    int j = (R / 48) * 16 + (R & 15);
    int slot = (R >> 4) % 3;                     // 0=r 1=z 2=n
    Wgh[i] = f2bf(Wih[(size_t)(slot * 256 + j) * 256 + k]);
    Wgs[i] = f2bf(Whh[(size_t)(slot * 256 + j) * 256 + k]);
  }
  for (int i = tid; i < 1024; i += nth) {
    int g = (i >> 4) & 3, j = ((i >> 6) << 4) + (i & 15);
    float v;
    if (g == 0)      v = bih[j] + bhh[j];
    else if (g == 1) v = bih[256 + j] + bhh[256 + j];
    else if (g == 2) v = bih[512 + j];
    else             v = bhh[512 + j];
    bg[i] = v;
  }
}

// ---------------- MFMA K-step (256x256 tile), full 4-j --------------------------
DEVI void mma8(const us* As, const us* Bs, int wr, int wc, int l,
               f32x4 (&acc)[8][4]) {
#pragma unroll
  for (int ks = 0; ks < 2; ++ks) {
    bf16x8 af[8], bfr[4];
#pragma unroll
    for (int i = 0; i < 8; ++i) {
      int row = wr * 128 + i * 16 + (l & 15);
      int kb = ((ks * 32 + (l >> 4) * 8) * 2) ^ ((row & 7) << 4);  // swizzled read
      af[i] = *(const bf16x8*)((const char*)As + row * 128 + kb);
    }
#pragma unroll
    for (int j = 0; j < 4; ++j) {
      int row = wc * 64 + j * 16 + (l & 15);
      int kb = ((ks * 32 + (l >> 4) * 8) * 2) ^ ((row & 7) << 4);
      bfr[j] = *(const bf16x8*)((const char*)Bs + row * 128 + kb);
    }
#pragma unroll
    for (int i = 0; i < 8; ++i)
#pragma unroll
      for (int j = 0; j < 4; ++j)
        acc[i][j] = __builtin_amdgcn_mfma_f32_16x16x32_bf16(af[i], bfr[j], acc[i][j], 0, 0, 0);
  }
}

// ---------------- MFMA phase (gates, 16-wave form): one ks, M=64 per wave ------
// slot 2 accumulates into acc[.][2] (xn) on the h-half (HN=0) and acc[.][3]
// (hn) on the s-half (HN=1). setprio around the MFMA cluster (T5).
template <int HN, int KS>
DEVI void mma4g_ks(const us* As, const us* Bs, int wr, int wc, int l,
                   f32x4 (&acc)[4][4]) {
  bf16x8 af[4], bfr[3];
#pragma unroll
  for (int i = 0; i < 4; ++i) {
    int row = wr * 64 + i * 16 + (l & 15);
    int kb = ((KS * 32 + (l >> 4) * 8) * 2) ^ ((row & 7) << 4);
    af[i] = *(const bf16x8*)((const char*)As + row * 128 + kb);
  }
#pragma unroll
  for (int j = 0; j < 3; ++j) {
    int row = wc * 48 + j * 16 + (l & 15);
    int kb = ((KS * 32 + (l >> 4) * 8) * 2) ^ ((row & 7) << 4);
    bfr[j] = *(const bf16x8*)((const char*)Bs + row * 128 + kb);
  }
  __builtin_amdgcn_s_setprio(1);
#pragma unroll
  for (int i = 0; i < 4; ++i)
#pragma unroll
    for (int j = 0; j < 3; ++j) {
      int aj = (j < 2) ? j : (HN ? 3 : 2);
      acc[i][aj] = __builtin_amdgcn_mfma_f32_16x16x32_bf16(af[i], bfr[j], acc[i][aj], 0, 0, 0);
    }
  __builtin_amdgcn_s_setprio(0);
}

// ---------------- resize GEMM: h0 = x(f32) @ Wr^T + bres -----------------------
__global__ __launch_bounds__(512, 2)
void k_gemm0(const float* __restrict__ x, const us* __restrict__ Bw,
             const float* __restrict__ bias, us* __restrict__ outBf) {
  __shared__ __align__(16) us As[256 * 64];
  __shared__ __align__(16) us Bs[256 * 64];
  int tid = threadIdx.x;
  int w = tid >> 6, l = tid & 63;
  int wr = w >> 2, wc = w & 3;
  int bid = blockIdx.x;
  int per = gridDim.x >> 3;
  int mi = (bid & 7) * per + (bid >> 3);
  int mBase = mi * 256;
  f32x4 acc[8][4] = {};

#pragma unroll
  for (int t = 0; t < 4; ++t) {
    int kt = t * 64;
#pragma unroll
    for (int c = 0; c < 4; ++c) {
      int row = c * 64 + (tid >> 3);
      int kbb = ((tid & 7) * 16) ^ ((row & 7) << 4);   // bf16-byte offset (swizzled src)
      const float* src = x + (size_t)(mBase + row) * 256 + kt + (kbb >> 1);
      float4 a = *(const float4*)src;
      float4 b = *(const float4*)(src + 4);
      us8 v;
      v[0] = f2bf(a.x); v[1] = f2bf(a.y); v[2] = f2bf(a.z); v[3] = f2bf(a.w);
      v[4] = f2bf(b.x); v[5] = f2bf(b.y); v[6] = f2bf(b.z); v[7] = f2bf(b.w);
      *(us8*)((char*)As + row * 128 + (tid & 7) * 16) = v;  // linear dest
      int kb = ((tid & 7) * 16) ^ ((row & 7) << 4);
      gload_lds16((const char*)(Bw + (size_t)row * 256 + kt) + kb,
                  (char*)Bs + row * 128 + (tid & 7) * 16);
    }
    asm volatile("s_waitcnt vmcnt(0)" ::: "memory");
    __syncthreads();                  // drains lgkm (ds_writes) + barrier
    mma8(As, Bs, wr, wc, l, acc);
    __syncthreads();
  }

  int rBase0 = mBase + wr * 128;
  int cBase0 = wc * 64;
#pragma unroll
  for (int i = 0; i < 8; ++i)
#pragma unroll
    for (int j = 0; j < 4; ++j) {
      int col = cBase0 + j * 16 + (l & 15);
      int row0 = rBase0 + i * 16 + ((l >> 4) << 2);
      float bb = bias[col];
#pragma unroll
      for (int e = 0; e < 4; ++e)
        outBf[(size_t)(row0 + e) * 256 + col] = f2bf(acc[i][j][e] + bb);
    }
}

// ---------------- s GEMM: s = [h[par] | avg(h[children])] @ Wcat^T + bcat ------
// R18 form (children-average inlined into staging). Unchanged.
__global__ __launch_bounds__(512, 2)
void k_sgemm(const us* __restrict__ h, const int* __restrict__ par,
             const int* __restrict__ chd, const int* __restrict__ cnt,
             const us* __restrict__ Wcat, const float* __restrict__ bcat,
             us* __restrict__ outBf, float* __restrict__ outF, int writeF32) {
  __shared__ __align__(16) us As[2][256 * 64];
  __shared__ __align__(16) us Bs[2][256 * 64];
  int tid = threadIdx.x;
  int w = tid >> 6, l = tid & 63;
  int wr = w >> 2, wc = w & 3;
  int bid = blockIdx.x;
  int per = gridDim.x >> 3;
  int mi = (bid & 7) * per + (bid >> 3);
  int mBase = mi * 256;
  int bb = (mBase >> 12) << 12;       // batch base row
  f32x4 acc[8][4] = {};

  int prow[4];
#pragma unroll
  for (int c = 0; c < 4; ++c)
    prow[c] = bb + par[mBase + c * 64 + (tid >> 3)];

  auto stageB = [&](int t) {
    int kt = t * 64, buf = t & 1;
#pragma unroll
    for (int c = 0; c < 4; ++c) {
      int row = c * 64 + (tid >> 3);
      int kb = ((tid & 7) * 16) ^ ((row & 7) << 4);
      gload_lds16((const char*)(Wcat + (size_t)row * 512 + kt) + kb,
                  (char*)Bs[buf] + row * 128 + (tid & 7) * 16);
    }
  };
  auto stageG = [&](int t) {          // tiles 0..3: h[parent] via gload (GA)
    int kt = t * 64, buf = t & 1;
#pragma unroll
    for (int c = 0; c < 4; ++c) {
      int row = c * 64 + (tid >> 3);
      int kb = ((tid & 7) * 16) ^ ((row & 7) << 4);
      gload_lds16((const char*)(h + (size_t)prow[c] * 256 + kt) + kb,
                  (char*)As[buf] + row * 128 + (tid & 7) * 16);
    }
    stageB(t);
  };
  auto stageN = [&](int t) {          // tiles 4..7: inline children-average
    int kt = t * 64, buf = t & 1;
    int kOffBase = kt - 256;
#pragma unroll
    for (int c = 0; c < 4; ++c) {
      int row = c * 64 + (tid >> 3);
      int m = mBase + row;
      int kbb = ((tid & 7) * 16) ^ ((row & 7) << 4);
      const us* hb = h + (size_t)bb * 256 + kOffBase + (kbb >> 1);
      int4 c0 = *(const int4*)(chd + (size_t)m * CC);
      int4 c1 = *(const int4*)(chd + (size_t)m * CC + 4);
      int ci[8] = {c0.x, c0.y, c0.z, c0.w, c1.x, c1.y, c1.z, c1.w};
      int cn = cnt[m];
      float aa[8] = {0.f, 0.f, 0.f, 0.f, 0.f, 0.f, 0.f, 0.f};
#pragma unroll
      for (int r2 = 0; r2 < 2; ++r2) {           // two rounds of 4 children
        us8 cv[4];
#pragma unroll
        for (int i2 = 0; i2 < 4; ++i2)
          cv[i2] = *(const us8*)(hb + (size_t)ci[r2 * 4 + i2] * 256);
#pragma unroll
        for (int i2 = 0; i2 < 4; ++i2) {
          float wgt = (r2 * 4 + i2 < cn) ? 1.f : 0.f;
#pragma unroll
          for (int e = 0; e < 8; ++e) aa[e] += wgt * bf2f(cv[i2][e]);
        }
      }
      float inv = 1.f / (float)cn;
      us8 nb;
#pragma unroll
      for (int e = 0; e < 8; ++e) nb[e] = f2bf(aa[e] * inv);
      *(us8*)((char*)As[buf] + row * 128 + (tid & 7) * 16) = nb;
    }
    asm volatile("s_waitcnt lgkmcnt(0)" ::: "memory");  // ds_writes done pre-barrier
    stageB(t);
  };

  stageG(0);
#pragma unroll
  for (int t = 0; t < 8; ++t) {
    if (t + 1 < 8) {
      if (t + 1 < 4) stageG(t + 1);
      else           stageN(t + 1);
    }
    if (t + 1 < 4)      asm volatile("s_waitcnt vmcnt(8)" ::: "memory");
    else if (t < 7)     asm volatile("s_waitcnt vmcnt(4)" ::: "memory");
    else                asm volatile("s_waitcnt vmcnt(0)" ::: "memory");
    raw_barrier();
    mma8(As[t & 1], Bs[t & 1], wr, wc, l, acc);
    raw_barrier();
  }

  int rBase0 = mBase + wr * 128;
  int cBase0 = wc * 64;
#pragma unroll
  for (int i = 0; i < 8; ++i)
#pragma unroll
    for (int j = 0; j < 4; ++j) {
      int col = cBase0 + j * 16 + (l & 15);
      int row0 = rBase0 + i * 16 + ((l >> 4) << 2);
      float bbia = bcat[col];
#pragma unroll
      for (int e = 0; e < 4; ++e) {
        float v = acc[i][j][e] + bbia;
        size_t off = (size_t)(row0 + e) * 256 + col;
        outBf[off] = f2bf(v);
        if (writeF32) outF[off] = v;
      }
    }
}

// ---------------- gates GEMM: [h|s] @ packed-Wg, 16-wave / 4 waves-per-SIMD ----
// R19: SAME block tile (256M x 192 packed), SAME LDS/staging/traffic as R18 —
// only the wave partition changes: 16 waves as 4(M)x4(N), per-wave M=64
// (acc[4][4]=64 regs, af[4], bfr[3] -> ~110 regs < the 128-reg budget a
// 1024-thread block forces). 4 waves/SIMD doubles latency-hiding TLP — the one
// axis never cleanly isolated (R9 confounded it with tile-size changes).
// Staging (1024 thr): A 2 loads/thread (c*128+(tid>>3)); B: waves 0-7 take 2,
// waves 8-15 take 1 (192 rows; wave-aligned guard). Counted vmcnt per group:
// steady 6/5, t==6: 4/3, tail 0. A triple-buffered depth-2, B double depth-1.
// Spill tripwire: WRITE_SIZE must stay ~33 MB (it<2) — else revert (R2 lesson).
__global__ __launch_bounds__(1024, 1)
void k_gates(const us* __restrict__ h, const us* __restrict__ s,
             const us* __restrict__ Wgh, const us* __restrict__ Wgs,
             const float* __restrict__ bg,
             us* __restrict__ outBf, float* __restrict__ outF,
             const us* __restrict__ svBf, const float* __restrict__ sF,
             int finalIt) {
  __shared__ __align__(16) us As[3][256 * 64];   // 96 KB (triple buffer, depth-2)
  __shared__ __align__(16) us Bs[2][192 * 64];   // 48 KB
  int tid = threadIdx.x;
  int w = tid >> 6, l = tid & 63;
  int wr = w >> 2, wc = w & 3;                   // 4(M) x 4(N)
  int bid = blockIdx.x;
  int per = gridDim.x >> 3;
  int g = (bid & 7) * per + (bid >> 3);
  int mi = g >> 2, ni = g & 3;                   // NT=4
  int mBase = mi * 256, nB = ni * 192, nBase = ni * 256;
  f32x4 acc[4][4] = {};

  auto stageA = [&](int t) {                     // 2 loads/thread -> As[t % 3]
    int buf = t % 3;
    const us* aSrc = (t < 4) ? h : s;
    int kOff = (t & 3) * 64;
#pragma unroll
    for (int c = 0; c < 2; ++c) {
      int row = c * 128 + (tid >> 3);
      int kb = ((tid & 7) * 16) ^ ((row & 7) << 4);
      gload_lds16((const char*)(aSrc + (size_t)(mBase + row) * 256 + kOff) + kb,
                  (char*)As[buf] + row * 128 + (tid & 7) * 16);
    }
  };
  auto stageBw = [&](int t) {                    // waves 0-7: 2 loads; 8-15: 1
    int buf = t & 1;
    const us* bSrc = (t < 4) ? Wgh : Wgs;
    int kOff = (t & 3) * 64;
    {
      int row = (tid >> 3);                      // rows 0..127
      int kb = ((tid & 7) * 16) ^ ((row & 7) << 4);
      gload_lds16((const char*)(bSrc + (size_t)(nB + row) * 256 + kOff) + kb,
                  (char*)Bs[buf] + row * 128 + (tid & 7) * 16);
    }
    if (w < 8) {                                 // rows 128..191 (wave-uniform)
      int row = 128 + (tid >> 3);
      int kb = ((tid & 7) * 16) ^ ((row & 7) << 4);
      gload_lds16((const char*)(bSrc + (size_t)(nB + row) * 256 + kOff) + kb,
                  (char*)Bs[buf] + row * 128 + (tid & 7) * 16);
    }
  };

  stageA(0); stageBw(0); stageA(1);
#pragma unroll
  for (int t = 0; t < 8; ++t) {
    if (t + 2 < 8) stageA(t + 2);
    if (t + 1 < 8) stageBw(t + 1);
    // counted per wave group: outstanding-beyond-(t) = A x2 tiles (2 each) + B x1
    if (t <= 5) {
      if (w < 8) asm volatile("s_waitcnt vmcnt(6)" ::: "memory");
      else       asm volatile("s_waitcnt vmcnt(5)" ::: "memory");
    } else if (t == 6) {
      if (w < 8) asm volatile("s_waitcnt vmcnt(4)" ::: "memory");
      else       asm volatile("s_waitcnt vmcnt(3)" ::: "memory");
    } else {
      asm volatile("s_waitcnt vmcnt(0)" ::: "memory");
    }
    raw_barrier();
    const us* A = As[t % 3];
    const us* B = Bs[t & 1];
    if (t < 4) {
      mma4g_ks<0, 0>(A, B, wr, wc, l, acc);      // slot2 -> xn
      mma4g_ks<0, 1>(A, B, wr, wc, l, acc);
    } else {
      mma4g_ks<1, 0>(A, B, wr, wc, l, acc);      // slot2 -> hn
      mma4g_ks<1, 1>(A, B, wr, wc, l, acc);
    }
    raw_barrier();
  }

  // shuffle-free GRU epilogue: acc j == gate {r, z, xn, hn}
  int rBase0 = mBase + wr * 64;
  int cB = nBase + wc * 64;
  int outCol = ((nBase >> 6) + wc) * 16 + (l & 15);
  float b0 = bg[cB + 0  + (l & 15)];
  float b1 = bg[cB + 16 + (l & 15)];
  float b2 = bg[cB + 32 + (l & 15)];
  float b3 = bg[cB + 48 + (l & 15)];
#pragma unroll
  for (int i = 0; i < 4; ++i) {
    int row0 = rBase0 + i * 16 + ((l >> 4) << 2);
#pragma unroll
    for (int e = 0; e < 4; ++e) {
      float r = sigf(acc[i][0][e] + b0);
      float z = sigf(acc[i][1][e] + b1);
      float n = tanhfast(acc[i][2][e] + b2 + r * (acc[i][3][e] + b3));
      size_t off = (size_t)(row0 + e) * 256 + outCol;
      float sv = finalIt ? sF[off] : bf2f(svBf[off]);
      float o = (1.f - z) * n + z * sv;
      if (finalIt) outF[off] = o;
      else         outBf[off] = f2bf(o);
    }
  }
}

extern "C" void kernel_launch(void* const* d_in, const int* in_sizes, int n_in,
                              void* d_out, int out_size, void* d_ws, size_t ws_size,
                              hipStream_t stream) {
  const float* x    = (const float*)d_in[0];
  const int*   par  = (const int*)d_in[1];
  const int*   chd  = (const int*)d_in[2];
  const int*   cnt  = (const int*)d_in[3];
  const float* Wres = (const float*)d_in[4];
  const float* bres = (const float*)d_in[5];
  const float* Wpar = (const float*)d_in[6];
  const float* bpar = (const float*)d_in[7];
  const float* Wnbr = (const float*)d_in[8];
  const float* bnbr = (const float*)d_in[9];
  const float* Wih  = (const float*)d_in[10];
  const float* Whh  = (const float*)d_in[11];
  const float* bih  = (const float*)d_in[12];
  const float* bhh  = (const float*)d_in[13];

  char* ws = (char*)d_ws;
  size_t off = 0;
  auto alloc = [&](size_t sz) { char* p = ws + off; off += (sz + 255) & ~(size_t)255; return p; };
  us*    Wgh  = (us*)alloc((size_t)768 * 256 * 2);
  us*    Wgs  = (us*)alloc((size_t)768 * 256 * 2);
  us*    Wcat = (us*)alloc((size_t)256 * 512 * 2);
  us*    Wr   = (us*)alloc((size_t)256 * 256 * 2);
  float* bcat = (float*)alloc(256 * 4);
  float* bg   = (float*)alloc(1024 * 4);
  us*    sbf  = (us*)alloc((size_t)MM * 256 * 2);
  us*    h0   = (us*)alloc((size_t)MM * 256 * 2);
  us*    h1   = (us*)alloc((size_t)MM * 256 * 2);
  float* sF   = (float*)d_out;  // f32 s scratch in d_out (final iter only;
                                // each slot overwritten after its own sv read)

  k_prep<<<256, 256, 0, stream>>>(Wres, Wpar, bpar, Wnbr, bnbr, Wih, Whh, bih, bhh,
                                  Wr, Wcat, bcat, Wgh, Wgs, bg);

  // h0 = x(f32) @ W_resize^T + b_resize   (direct f32 read)
  k_gemm0<<<256, 512, 0, stream>>>(x, Wr, bres, h0);

  us* hc = h0;
  for (int it = 0; it < 3; ++it) {
    us* hn = (hc == h0) ? h1 : h0;
    // s = [h[par] | avg(h[children])] @ Wcat^T + bcat
    k_sgemm<<<256, 512, 0, stream>>>(hc, par, chd, cnt, Wcat, bcat,
                                     sbf, sF, (it == 2) ? 1 : 0);
    // gates = [h|s] @ packed-Wg, fused GRU -> h_next (bf16) or d_out (f32)
    k_gates<<<1024, 1024, 0, stream>>>(
        hc, sbf, Wgh, Wgs, bg, hn, (float*)d_out, sbf, sF, (it == 2) ? 1 : 0);
    hc = hn;
  }
}